// Round 3
// baseline (31983.163 us; speedup 1.0000x reference)
//
#include <hip/hip_runtime.h>
#include <hip/hip_bf16.h>

#define H      1000          // hidden dim
#define HP     1024          // padded hidden (packet elements)
#define TT     8192          // seq len
#define NC     68            // num chars
#define SL     64            // wave size
#define NWAVE  128           // 16 row slices x 8 col chunks
#define PRING  4             // packet ring slots
#define POLL_LIMIT 32768u    // sweeps before declaring the fast path dead
#define PF_LIMIT   8192u     // preflight probe sweeps
#define BAR_LIMIT  32768u    // barrier spin limit (agent loads)
#define TM     16            // t-tile for output gemm
#define GRID_FAST 2048       // oversubscribed launch; cohort self-assembles on XCD 0
#define PF_MAGIC 0x1DEADBEEFull

typedef unsigned long long u64;
typedef long long ll;

// ---------------------------------------------------------------------------
// FAST PATH v3: preflight-gated dual-mode cohort.
//
// 2048 one-wave blocks launch; blocks with HW_REG_XCC_ID!=0 exit; XCD-0
// blocks claim ranks 0..127 (agent atomic), rest exit. Then:
//
//   PREFLIGHT: rank 0 plain-stores PF_MAGIC to a probe line (lands dirty in
//   XCD-0's L2 via the write-through L1). All waves poll it with
//   {buffer_inv sc0; plain load} (bounded). A wave that cannot see it flags
//   the mode word (agent/MALL scope). After a barrier, everyone reads the
//   mode word:
//
//   MODE L2 (all saw it => cohort is co-XCD and inv+store visibility works):
//     tagged-store protocol, fb-proven mechanism class but same-XCD:
//     producer (b,cc) lane rl plain-stores ((want<<32)|f32bits(partial)) to
//     pkt_st[slot][cc][row]  (single 8B store = tag+payload atomic).
//     Consumer polls 8 tags per element with buffer_inv+volatile loads until
//     all == want, then sums the 8 f32 partials in fixed order (bit-identical
//     across the 16 redundant finalizers), h = tanh(xh + sum + bias).
//     pkt_st is self-zeroed through the SAME L2 path before the loop (kills
//     cross-iteration stale tags). NO atomics anywhere on the fast path -
//     round 2's suspected failure was atomic routing past the XCD L2.
//
//   MODE MALL (any wave failed preflight - scattered cohort or broken inv):
//     EXACTLY the proven round-0 protocol (14.0 ms): agent-scope
//     fixed-point count|value atomics + agent-scope poll loads at the MALL.
//
// Ring safety (both modes, PRING=4): a producer writing @want+4 completed
// its poll @want+3, which transitively spans ALL 16 slices at @want+2, so no
// poller of `want` can observe writes from a later ring generation. L2 mode
// additionally has absolute tags (no modular ambiguity after self-zeroing).
//
// Liveness: every spin (barriers, preflight, polls) is bounded; any overrun
// => wave returns; `done` stays < 8 and the proven R3 fallback recomputes
// ALL of h_all. Participants never depend on non-participants. No hang.
// ---------------------------------------------------------------------------

__device__ __forceinline__ bool bar_wait(int* ctr, int rl)
{
    // drain prior vm ops so everything this wave published is complete
    // before its arrival is visible (ordering across two MALL addresses)
    asm volatile("s_waitcnt vmcnt(0)" ::: "memory");
    if (rl == 0)
        __hip_atomic_fetch_add(ctr, 1, __ATOMIC_RELAXED,
                               __HIP_MEMORY_SCOPE_AGENT);
    unsigned n = 0;
    while (__hip_atomic_load(ctr, __ATOMIC_RELAXED,
                             __HIP_MEMORY_SCOPE_AGENT) < NWAVE) {
        if (++n > BAR_LIMIT) return false;
    }
    return true;
}

__global__ __launch_bounds__(64, 1) void rnn_fast(
    const int*   __restrict__ x_idx,
    const float* __restrict__ W_xhT,   // NC x H
    const float* __restrict__ W_hh,
    const float* __restrict__ B_h,
    float*       __restrict__ h_all,   // (TT+1) x H
    u64*         __restrict__ pkt_at,  // [PRING][HP]      (MALL mode, zeroed)
    u64*         __restrict__ pkt_st,  // [PRING][8][HP]   (L2 mode)
    int*         __restrict__ ctrl,    // [0]=claim [1..3]=barriers [4]=mode
    u64*         __restrict__ probe,   // preflight line (own 256B region)
    int*         __restrict__ done)    // completion counter, pre-zeroed
{
    // --- cohort self-assembly on XCD 0 ---
    unsigned xcc;
    asm volatile("s_getreg_b32 %0, hwreg(HW_REG_XCC_ID)" : "=s"(xcc));
    if ((xcc & 7u) != 0u) return;

    const int rl = threadIdx.x;
    int rank = 0;
    if (rl == 0)
        rank = __hip_atomic_fetch_add(&ctrl[0], 1, __ATOMIC_RELAXED,
                                      __HIP_MEMORY_SCOPE_AGENT);
    rank = __builtin_amdgcn_readfirstlane(rank);
    if (rank >= NWAVE) return;

    // --- preflight store (before barrier 1) ---
    if (rank == 0 && rl == 0)
        *probe = PF_MAGIC;               // plain store -> dirty in XCD-0 L2

    if (!bar_wait(&ctrl[1], rl)) return;

    // --- preflight poll: can THIS wave see a same-XCD plain store? ---
    bool l2ok = false;
    {
        u64 pv = 0;
        for (unsigned n = 0; n < PF_LIMIT; ++n) {
            asm volatile(
                "buffer_inv sc0\n\t"
                "global_load_dwordx2 %0, %1, off\n\t"
                "s_waitcnt vmcnt(0)"
                : "=&v"(pv) : "v"(probe) : "memory");
            if (pv == (u64)PF_MAGIC) { l2ok = true; break; }
        }
    }
    if (!l2ok && rl == 0)
        __hip_atomic_fetch_add(&ctrl[4], 1, __ATOMIC_RELAXED,
                               __HIP_MEMORY_SCOPE_AGENT);
    if (!bar_wait(&ctrl[2], rl)) return;   // vmcnt drain orders flag<barrier
    const bool modeL2 =
        (__hip_atomic_load(&ctrl[4], __ATOMIC_RELAXED,
                           __HIP_MEMORY_SCOPE_AGENT) == 0);

    // --- common setup ---
    const int b  = rank >> 3;                 // row slice 0..15
    const int cc = rank & 7;                  // col chunk 0..7
    const int row = b * SL + rl;              // producer row (<= 1023)
    const int e0  = cc * 128 + rl;            // consumer elements (e0 <= 959)
    const int e1  = e0 + 64;                  // (e1 <= 1023)
    const bool rowv = (row < H);
    const bool v1   = (e1 < H);

    float w[128];
    const float* wrow = W_hh + (size_t)row * H;
    #pragma unroll
    for (int q = 0; q < 32; ++q) {
        const int k = cc * 128 + 4 * q;
        float4 v = make_float4(0.f, 0.f, 0.f, 0.f);
        if (rowv && (k + 3) < H) v = *(const float4*)(wrow + k);
        w[4*q+0] = v.x; w[4*q+1] = v.y; w[4*q+2] = v.z; w[4*q+3] = v.w;
    }
    const float bi0 = B_h[e0];
    const float bi1 = v1 ? B_h[e1] : 0.f;

    __shared__ float sh[128];                 // my h-chunk
    sh[rl]      = h_all[e0];
    sh[64 + rl] = v1 ? h_all[e1] : 0.f;
    asm volatile("s_waitcnt lgkmcnt(0)" ::: "memory");

    int xi = x_idx[0];

#define FMA128(AOUT)                                                          \
    float AOUT;                                                               \
    {                                                                         \
        float a0 = 0.f, a1 = 0.f, a2 = 0.f, a3 = 0.f;                         \
        const float4* hb = (const float4*)sh;                                 \
        _Pragma("unroll")                                                     \
        for (int q = 0; q < 32; ++q) {                                        \
            const float4 hv4 = hb[q];                                         \
            a0 += w[4*q+0] * hv4.x;                                           \
            a1 += w[4*q+1] * hv4.y;                                           \
            a2 += w[4*q+2] * hv4.z;                                           \
            a3 += w[4*q+3] * hv4.w;                                           \
        }                                                                     \
        AOUT = (a0 + a1) + (a2 + a3);                                         \
    }

    if (modeL2) {
        // ---- self-zero pkt_st through the L2 path (kills stale tags) ----
        const int gid = rank * SL + rl;               // 0..8191
        #pragma unroll
        for (int z = 0; z < 4; ++z)
            pkt_st[(size_t)z * 8192 + gid] = 0;       // 4*8192 = 32768 u64
        if (!bar_wait(&ctrl[3], rl)) return;

        // ---- L2-mode main loop: tagged-store protocol ----
        for (int t = 0; t < TT; ++t) {
            const int want = t + 1;
            int xi_nxt = xi;
            if (want < TT) xi_nxt = x_idx[want];
            const float xh0 = W_xhT[(size_t)xi * H + e0];
            const float xh1 = v1 ? W_xhT[(size_t)xi * H + e1] : 0.f;
            FMA128(a)
            const int slot = want & (PRING - 1);
            // publish: single 8B plain store (tag|payload), lands in XCD-0 L2
            pkt_st[((size_t)slot * 8 + cc) * HP + row] =
                ((u64)(unsigned)want << 32) | (u64)__float_as_uint(a);
            asm volatile("" ::: "memory");
            // poll: 8 producer tags per element, inv + volatile loads
            volatile const u64* vp = pkt_st + (size_t)slot * 8 * HP;
            u64 q0[8], q1[8];
            unsigned sweeps = 0;
            for (;;) {
                asm volatile("buffer_inv sc0" ::: "memory");
                bool ok = true;
                #pragma unroll
                for (int j = 0; j < 8; ++j) {
                    q0[j] = vp[j * HP + e0];
                    q1[j] = vp[j * HP + e1];
                }
                #pragma unroll
                for (int j = 0; j < 8; ++j) {
                    ok &= ((unsigned)(q0[j] >> 32) == (unsigned)want);
                    ok &= ((unsigned)(q1[j] >> 32) == (unsigned)want);
                }
                if (__all(ok)) break;
                if (++sweeps > POLL_LIMIT) return;   // cohort dead: bail
            }
            float s0 = xh0 + bi0, s1 = xh1 + bi1;
            #pragma unroll
            for (int j = 0; j < 8; ++j) {
                s0 += __uint_as_float((unsigned)q0[j]);
                s1 += __uint_as_float((unsigned)q1[j]);
            }
            const float h0v = tanhf(s0);
            const float h1v = v1 ? tanhf(s1) : 0.f;
            if (want < TT) {
                sh[rl]      = h0v;
                sh[64 + rl] = h1v;
                asm volatile("s_waitcnt lgkmcnt(0)" ::: "memory");
            }
            if (b == cc) {                   // 8 designated writer waves
                h_all[(size_t)want * H + e0] = h0v;
                if (v1) h_all[(size_t)want * H + e1] = h1v;
            }
            xi = xi_nxt;
        }
    } else {
        // ---- MALL-mode main loop: EXACT round-0 proven protocol ----
        ll old0 = 0, old1 = 0, old2 = 0, old3 = 0;

#define RSTEP(WANT, SLOT, OLDV)                                               \
    {                                                                         \
        const int want = (WANT);                                              \
        int xi_nxt = xi;                                                      \
        if (want < TT) xi_nxt = x_idx[want];                                  \
        const float xh0 = W_xhT[(size_t)xi * H + e0];                         \
        const float xh1 = v1 ? W_xhT[(size_t)xi * H + e1] : 0.f;              \
        FMA128(a)                                                             \
        const ll ev = (ll)(a * 4294967296.0f);                                \
        __hip_atomic_fetch_add(pkt_at + (SLOT) * HP + row,                    \
                               ((u64)(ev - (OLDV)) << 16) | 1ull,             \
                               __ATOMIC_RELAXED, __HIP_MEMORY_SCOPE_AGENT);   \
        (OLDV) = ev;                                                          \
        asm volatile("" ::: "memory");                                        \
        const unsigned expected = 8u * ((unsigned)(want + 3) >> 2);           \
        u64* q0p = pkt_at + (SLOT) * HP + e0;                                 \
        u64 p0, p1;                                                           \
        unsigned sweeps = 0;                                                  \
        for (;;) {                                                            \
            p0 = __hip_atomic_load(q0p, __ATOMIC_RELAXED,                     \
                                   __HIP_MEMORY_SCOPE_AGENT);                 \
            p1 = __hip_atomic_load(q0p + 64, __ATOMIC_RELAXED,                \
                                   __HIP_MEMORY_SCOPE_AGENT);                 \
            const bool ok = ((unsigned)(p0 & 0xFFFFull) == expected) &        \
                            ((unsigned)(p1 & 0xFFFFull) == expected);         \
            if (__all(ok)) break;                                             \
            if (++sweeps > POLL_LIMIT) return;                                \
        }                                                                     \
        const float z0 = (float)((double)((ll)p0 >> 16) *                     \
                                 (1.0 / 4294967296.0)) + xh0 + bi0;           \
        const float z1 = (float)((double)((ll)p1 >> 16) *                     \
                                 (1.0 / 4294967296.0)) + xh1 + bi1;           \
        const float h0v = tanhf(z0);                                          \
        const float h1v = v1 ? tanhf(z1) : 0.f;                               \
        if (want < TT) {                                                      \
            sh[rl]      = h0v;                                                \
            sh[64 + rl] = h1v;                                                \
            asm volatile("s_waitcnt lgkmcnt(0)" ::: "memory");                \
        }                                                                     \
        if (b == cc) {                                                        \
            h_all[(size_t)want * H + e0] = h0v;                               \
            if (v1) h_all[(size_t)want * H + e1] = h1v;                       \
        }                                                                     \
        xi = xi_nxt;                                                          \
    }

        for (int tb = 0; tb < TT; tb += PRING) {
            RSTEP(tb + 1, 1, old1)
            RSTEP(tb + 2, 2, old2)
            RSTEP(tb + 3, 3, old3)
            RSTEP(tb + 4, 0, old0)
        }
#undef RSTEP
    }
#undef FMA128

    if (b == cc && rl == 0)
        __hip_atomic_fetch_add(done, 1, __ATOMIC_RELAXED,
                               __HIP_MEMORY_SCOPE_AGENT);
}

// ---------------------------------------------------------------------------
// FALLBACK: proven R3 agent-scope path (15.2ms). Skipped iff the fast cohort
// fully completed (done == 8) and the fast path was attempted (fail == 0).
// ---------------------------------------------------------------------------
#define FB_RING 4
__global__ __launch_bounds__(64) void rnn_fb(
    const int*   __restrict__ x_idx,
    const float* __restrict__ W_xhT,
    const float* __restrict__ W_hh,
    const float* __restrict__ B_h,
    float*       __restrict__ h_all,
    u64*         __restrict__ pkt,     // FB_RING x 16 x 16 x SL
    const int*   __restrict__ fail,
    const int*   __restrict__ done)
{
    if (__hip_atomic_load(fail, __ATOMIC_RELAXED,
                          __HIP_MEMORY_SCOPE_AGENT) == 0 &&
        __hip_atomic_load(done, __ATOMIC_RELAXED,
                          __HIP_MEMORY_SCOPE_AGENT) == 8)
        return;                               // fast path delivered h_all

    const int rl  = threadIdx.x;
    const int b   = blockIdx.x >> 4;
    const int cc  = blockIdx.x & 15;
    const int row = b * SL + rl;
    const int r   = cc * SL + rl;
    const bool rowv = (row < H);
    const bool rv   = (r < H);

    float w[SL];
    const float* wrow = W_hh + (size_t)row * H;
    #pragma unroll
    for (int q = 0; q < SL / 4; ++q) {
        const int k = cc * SL + 4 * q;
        float4 v = make_float4(0.f, 0.f, 0.f, 0.f);
        if (rowv && (k + 3) < H) v = *(const float4*)(wrow + k);
        w[4*q+0] = v.x; w[4*q+1] = v.y; w[4*q+2] = v.z; w[4*q+3] = v.w;
    }
    const float bh = rv ? B_h[r] : 0.f;

    __shared__ float sh[SL];
    sh[rl] = rv ? h_all[r] : 0.f;
    asm volatile("s_waitcnt lgkmcnt(0)" ::: "memory");

    int xi = x_idx[0];
    for (int t = 0; t < TT; ++t) {
        const unsigned want = (unsigned)(t + 1);
        const int slot = (int)(want & (FB_RING - 1));
        int xi_nxt = xi;
        if (t + 1 < TT) xi_nxt = x_idx[t + 1];
        float xh = 0.f;
        if (rv) xh = W_xhT[(size_t)xi * H + r];

        float a0 = 0.f, a1 = 0.f, a2 = 0.f, a3 = 0.f;
        const float4* hb = (const float4*)sh;
        #pragma unroll
        for (int q = 0; q < SL / 4; ++q) {
            const float4 hv4 = hb[q];
            a0 += w[4*q+0] * hv4.x;
            a1 += w[4*q+1] * hv4.y;
            a2 += w[4*q+2] * hv4.z;
            a3 += w[4*q+3] * hv4.w;
        }
        const float a = (a0 + a1) + (a2 + a3);

        __hip_atomic_store(pkt + (((size_t)slot * 16 + b) * 16 + cc) * SL + rl,
                           ((u64)want << 32) | (u64)__float_as_uint(a),
                           __ATOMIC_RELAXED, __HIP_MEMORY_SCOPE_AGENT);

        const u64* base = pkt + ((size_t)slot * 16 + cc) * 16 * SL + rl;
        u64 p[16];
        for (;;) {
            #pragma unroll
            for (int j = 0; j < 16; ++j)
                p[j] = __hip_atomic_load(base + j * SL, __ATOMIC_RELAXED,
                                         __HIP_MEMORY_SCOPE_AGENT);
            bool ok = true;
            #pragma unroll
            for (int j = 0; j < 16; ++j)
                ok &= ((unsigned)(p[j] >> 32) == want);
            if (__all(ok)) break;
        }

        float s = xh + bh;
        #pragma unroll
        for (int j = 0; j < 16; ++j) s += __uint_as_float((unsigned)p[j]);
        const float hv = rv ? tanhf(s) : 0.f;
        if (b == cc && rv) h_all[(size_t)want * H + r] = hv;
        sh[rl] = hv;
        asm volatile("s_waitcnt lgkmcnt(0)" ::: "memory");
        xi = xi_nxt;
    }
}

// ---------------------------------------------------------------------------
__global__ __launch_bounds__(256) void transpose_wxh(
    const float* __restrict__ W_xh, float* __restrict__ W_xhT)
{
    const int idx = blockIdx.x * 256 + threadIdx.x;
    if (idx < NC * H) {
        const int c = idx / H, r = idx % H;
        W_xhT[idx] = W_xh[r * NC + c];
    }
}

__global__ __launch_bounds__(256) void transpose_why(
    const float* __restrict__ W_hy, float* __restrict__ WhyT)
{
    const int idx = blockIdx.x * 256 + threadIdx.x;
    if (idx < NC * H) {
        const int k = idx / NC, n = idx % NC;
        WhyT[idx] = W_hy[n * H + k];
    }
}

__global__ __launch_bounds__(256) void out_gemm(
    const float* __restrict__ h_all,
    const float* __restrict__ WhyT,   // padded by >=16 floats
    float*       __restrict__ out)
{
    __shared__ float hs[TM * H];      // 64000 B
    const int t0 = blockIdx.x * TM;
    const int nt = min(TM, (TT + 1) - t0);

    const float4* src = (const float4*)(h_all + (size_t)t0 * H);
    const int total4 = nt * H / 4;
    for (int i = threadIdx.x; i < total4; i += 256)
        ((float4*)hs)[i] = src[i];
    __syncthreads();

    const int tl = threadIdx.x >> 4;
    const int ng = threadIdx.x & 15;
    if (tl < nt) {
        float acc0 = 0.f, acc1 = 0.f, acc2 = 0.f, acc3 = 0.f, acc4 = 0.f;
        const float* hrow = hs + tl * H;
        #pragma unroll 4
        for (int k = 0; k < H; ++k) {
            const float hv = hrow[k];
            const float* wr = WhyT + k * NC + ng;
            acc0 += hv * wr[0];
            acc1 += hv * wr[16];
            acc2 += hv * wr[32];
            acc3 += hv * wr[48];
            acc4 += hv * wr[64];
        }
        float* orow = out + (size_t)(t0 + tl) * NC + ng;
        orow[0]  = acc0;
        orow[16] = acc1;
        orow[32] = acc2;
        orow[48] = acc3;
        if (ng < 4) orow[64] = acc4;
    }
}

// ---------------------------------------------------------------------------
extern "C" void kernel_launch(void* const* d_in, const int* in_sizes, int n_in,
                              void* d_out, int out_size, void* d_ws, size_t ws_size,
                              hipStream_t stream)
{
    const int*   x_idx = (const int*)  d_in[0];
    const float* h0    = (const float*)d_in[1];
    const float* W_xh  = (const float*)d_in[2];
    const float* W_hh  = (const float*)d_in[3];
    const float* W_hy  = (const float*)d_in[4];
    const float* B_h   = (const float*)d_in[5];
    float* out = (float*)d_out;

    char* ws = (char*)d_ws;
    size_t off = 0;
    auto take = [&](size_t bytes) {
        void* p = ws + off;
        off = (off + bytes + 255) & ~(size_t)255;
        return p;
    };
    float* h_all  = (float*)take((size_t)(TT + 1) * H * sizeof(float));
    float* WhyT   = (float*)take((size_t)(NC * H + 32) * sizeof(float));
    float* W_xhT  = (float*)take((size_t)(NC * H) * sizeof(float));
    const size_t fb_bytes = (size_t)FB_RING * 16 * 16 * SL * sizeof(u64);
    u64*   pkt_fb = (u64*)take(fb_bytes);
    int*   fail   = (int*)take(64);
    int*   done   = (int*)take(64);
    int*   ctrl   = (int*)take(256);       // own cache lines
    u64*   probe  = (u64*)take(256);       // own cache line (may go L2-dirty)
    const size_t at_bytes = (size_t)PRING * HP * sizeof(u64);       // 32 KB
    u64*   pkt_at = (u64*)take(at_bytes);
    const size_t st_bytes = (size_t)PRING * 8 * HP * sizeof(u64);   // 256 KB
    u64*   pkt_st = (u64*)take(st_bytes);
    const size_t need_fast = off;

    hipMemcpyAsync(h_all, h0, H * sizeof(float),
                   hipMemcpyDeviceToDevice, stream);
    transpose_wxh<<<(NC * H + 255) / 256, 256, 0, stream>>>(W_xh, W_xhT);
    transpose_why<<<(NC * H + 255) / 256, 256, 0, stream>>>(W_hy, WhyT);

    hipMemsetAsync(pkt_fb, 0, fb_bytes, stream);
    hipMemsetAsync(done, 0, 64, stream);
    if (ws_size >= need_fast) {
        hipMemsetAsync(pkt_at, 0, at_bytes, stream);
        hipMemsetAsync(ctrl, 0, 256, stream);
        hipMemsetAsync(probe, 0, 256, stream);
        hipMemsetAsync(fail, 0, 64, stream);
        rnn_fast<<<GRID_FAST, SL, 0, stream>>>(x_idx, W_xhT, W_hh, B_h,
                                               h_all, pkt_at, pkt_st,
                                               ctrl, probe, done);
    } else {
        hipMemsetAsync(fail, 1, 4, stream);    // force fallback
    }
    rnn_fb<<<256, SL, 0, stream>>>(x_idx, W_xhT, W_hh, B_h,
                                   h_all, pkt_fb, fail, done);
    out_gemm<<<(TT + 1 + TM - 1) / TM, 256, 0, stream>>>(h_all, WhyT, out);
}

// Round 4
// 30156.790 us; speedup vs baseline: 1.0606x; 1.0606x over previous
//
#include <hip/hip_runtime.h>
#include <hip/hip_bf16.h>

#define H      1000          // hidden dim
#define HP     1024          // padded hidden (packet elements)
#define TT     8192          // seq len
#define NC     68            // num chars
#define SL     64            // wave size
#define NWAVE  128           // 16 row slices x 8 col chunks
#define PRING  4             // packet ring slots
#define POLL_LIMIT 32768u    // sweeps before declaring the fast path dead
#define PF_A_LIMIT 4096u     // preflight sc0-only probe sweeps
#define PF_B_LIMIT 8192u     // preflight inv+load probe sweeps
#define BAR_LIMIT  16384u    // barrier spin limit (agent loads)
#define TM     16            // t-tile for output gemm
#define GRID_FAST 2048       // oversubscribed launch; cohort self-assembles on XCD 0
#define PF_MAGIC 0x1DEADBEEFull

typedef unsigned long long u64;
typedef long long ll;
typedef unsigned u32x4 __attribute__((ext_vector_type(4)));

// ---------------------------------------------------------------------------
// FAST PATH v4: three-mode preflight + single-round-trip poll.
//
// Round-3 PROVED: cohort assembles on XCD 0; plain stores land dirty in
// XCD-0's L2; {buffer_inv sc0 + load} observes them; packet protocol is
// correct (WRITE_SIZE collapsed 556MB -> 32MB = h_all only). Round-3's
// slowness was the poll: 16 VOLATILE loads => LLVM inserts s_waitcnt
// vmcnt(0) after EACH => 16 serialized L2 round trips (~3us) per sweep.
//
// v4 poll: element-major packets pkt[slot][element][producer] so each
// element's 8 (payload|tag) u64s are 64B contiguous; one asm block issues
// 8 global_load_dwordx4 (both elements) with ONE s_waitcnt vmcnt(0):
// a sweep is now a single pipelined L2 round trip.
//
// Preflight (per wave, consensus by counters):
//   prime L1 with the probe line (plain load) -> barrier -> rank0 plain-
//   stores PF_MAGIC -> poll A: sc0-only loads (tests whether sc0 bypasses
//   L1; round-1's failure was the publish-atomic executing at the MALL, so
//   sc0-load behavior was never actually falsified) -> failers poll B:
//   buffer_inv + load (round-3-proven) -> consensus:
//     all passed A            => MODE 0: sc0-poll, no inv (keeps L1 warm)
//     some failed A, all B ok => MODE 1: inv + poll (round-3 mechanism)
//     else                    => MODE 2: round-0 proven MALL protocol (14ms)
//
// Tags: producer (b,cc) lane rl stores ((want<<32)|f32bits(partial)) to
// pkt[slot][row][cc] (one 8B store). Consumer breaks when all 16 tags
// (8 producers x 2 elements) == want; payloads ride in the same 8B words
// (8B halves of a dwordx4 are consistent: single >=16B L2 access). Sum in
// fixed j-order => bit-identical across the 16 redundant finalizers.
// Self-zero of pkt through the L2 path kills cross-run stale tags (a
// PREVIOUS kernel iteration leaves tags up to 8192 that would alias
// want==8188.. at ring reuse -- round-3 handled identically).
//
// Ring safety (PRING=4): a producer storing @want+4 completed its poll
// @want+3, which transitively spans ALL 16 slices at @want+2, so no poller
// of `want` can observe a later ring generation. Tag equality is exact.
//
// Liveness: every spin (barriers, preflight, polls) is bounded; any overrun
// => wave returns; `done` stays < 8 and the proven R3 fallback recomputes
// ALL of h_all. Participants never depend on non-participants. No hang.
// ---------------------------------------------------------------------------

__device__ __forceinline__ bool bar_wait(int* ctr, int rl)
{
    // drain own vm ops so everything published is complete before arrival
    asm volatile("s_waitcnt vmcnt(0)" ::: "memory");
    if (rl == 0)
        __hip_atomic_fetch_add(ctr, 1, __ATOMIC_RELAXED,
                               __HIP_MEMORY_SCOPE_AGENT);
    unsigned n = 0;
    while (__hip_atomic_load(ctr, __ATOMIC_RELAXED,
                             __HIP_MEMORY_SCOPE_AGENT) < NWAVE) {
        if (++n > BAR_LIMIT) return false;
    }
    return true;
}

__global__ __launch_bounds__(64, 1) void rnn_fast(
    const int*   __restrict__ x_idx,
    const float* __restrict__ W_xhT,   // NC x H
    const float* __restrict__ W_hh,
    const float* __restrict__ B_h,
    float*       __restrict__ h_all,   // (TT+1) x H
    u64*         __restrict__ pkt_at,  // [PRING][HP]        (MALL mode, zeroed)
    u64*         __restrict__ pkt_st,  // [PRING][HP][8]     (L2 modes)
    int*         __restrict__ ctrl,    // [0]=claim [1..3]=bars [4]=fA [5]=fB
    u64*         __restrict__ probe,   // preflight line (own 256B region)
    int*         __restrict__ done)    // completion counter, pre-zeroed
{
    // --- cohort self-assembly on XCD 0 ---
    unsigned xcc;
    asm volatile("s_getreg_b32 %0, hwreg(HW_REG_XCC_ID)" : "=s"(xcc));
    if ((xcc & 7u) != 0u) return;

    const int rl = threadIdx.x;
    int rank = 0;
    if (rl == 0)
        rank = __hip_atomic_fetch_add(&ctrl[0], 1, __ATOMIC_RELAXED,
                                      __HIP_MEMORY_SCOPE_AGENT);
    rank = __builtin_amdgcn_readfirstlane(rank);
    if (rank >= NWAVE) return;

    // --- preflight: prime L1 with the (stale) probe line ---
    {
        u64 primed;
        asm volatile(
            "global_load_dwordx2 %0, %1, off\n\t"
            "s_waitcnt vmcnt(0)"
            : "=&v"(primed) : "v"(probe) : "memory");
        asm volatile("" :: "v"(primed));          // keep the prime alive
    }
    if (!bar_wait(&ctrl[1], rl)) return;

    if (rank == 0 && rl == 0)
        *probe = PF_MAGIC;                        // plain store -> L2 dirty
    asm volatile("s_waitcnt vmcnt(0)" ::: "memory");

    // --- poll A: do sc0 loads bypass the (primed, stale) L1? ---
    bool okA = false;
    {
        u64 pv = 0;
        for (unsigned n = 0; n < PF_A_LIMIT; ++n) {
            asm volatile(
                "global_load_dwordx2 %0, %1, off sc0\n\t"
                "s_waitcnt vmcnt(0)"
                : "=&v"(pv) : "v"(probe) : "memory");
            if (pv == (u64)PF_MAGIC) { okA = true; break; }
        }
    }
    if (!okA && rl == 0)
        __hip_atomic_fetch_add(&ctrl[4], 1, __ATOMIC_RELAXED,
                               __HIP_MEMORY_SCOPE_AGENT);
    // --- poll B (only if A failed): inv + load (round-3-proven) ---
    if (!okA) {
        bool okB = false;
        u64 pv = 0;
        for (unsigned n = 0; n < PF_B_LIMIT; ++n) {
            asm volatile(
                "buffer_inv sc0\n\t"
                "global_load_dwordx2 %0, %1, off\n\t"
                "s_waitcnt vmcnt(0)"
                : "=&v"(pv) : "v"(probe) : "memory");
            if (pv == (u64)PF_MAGIC) { okB = true; break; }
        }
        if (!okB && rl == 0)
            __hip_atomic_fetch_add(&ctrl[5], 1, __ATOMIC_RELAXED,
                                   __HIP_MEMORY_SCOPE_AGENT);
    }
    if (!bar_wait(&ctrl[2], rl)) return;
    const int failA = __hip_atomic_load(&ctrl[4], __ATOMIC_RELAXED,
                                        __HIP_MEMORY_SCOPE_AGENT);
    const int failB = __hip_atomic_load(&ctrl[5], __ATOMIC_RELAXED,
                                        __HIP_MEMORY_SCOPE_AGENT);
    const int mode = (failA == 0) ? 0 : ((failB == 0) ? 1 : 2);

    // --- common setup ---
    const int b  = rank >> 3;                 // row slice 0..15
    const int cc = rank & 7;                  // col chunk 0..7
    const int row = b * SL + rl;              // producer row (<= 1023)
    const int e0  = cc * 128 + rl;            // consumer elements (e0 <= 959)
    const int e1  = e0 + 64;                  // (e1 <= 1023)
    const bool rowv = (row < H);
    const bool v1   = (e1 < H);

    float w[128];
    const float* wrow = W_hh + (size_t)row * H;
    #pragma unroll
    for (int q = 0; q < 32; ++q) {
        const int k = cc * 128 + 4 * q;
        float4 v = make_float4(0.f, 0.f, 0.f, 0.f);
        if (rowv && (k + 3) < H) v = *(const float4*)(wrow + k);
        w[4*q+0] = v.x; w[4*q+1] = v.y; w[4*q+2] = v.z; w[4*q+3] = v.w;
    }
    const float bi0 = B_h[e0];
    const float bi1 = v1 ? B_h[e1] : 0.f;

    __shared__ float sh[128];                 // my h-chunk
    sh[rl]      = h_all[e0];
    sh[64 + rl] = v1 ? h_all[e1] : 0.f;
    asm volatile("s_waitcnt lgkmcnt(0)" ::: "memory");

    int xi = x_idx[0];

#define FMA128(AOUT)                                                          \
    float AOUT;                                                               \
    {                                                                         \
        float a0 = 0.f, a1 = 0.f, a2 = 0.f, a3 = 0.f;                         \
        const float4* hb = (const float4*)sh;                                 \
        _Pragma("unroll")                                                     \
        for (int q = 0; q < 32; ++q) {                                        \
            const float4 hv4 = hb[q];                                         \
            a0 += w[4*q+0] * hv4.x;                                           \
            a1 += w[4*q+1] * hv4.y;                                           \
            a2 += w[4*q+2] * hv4.z;                                           \
            a3 += w[4*q+3] * hv4.w;                                           \
        }                                                                     \
        AOUT = (a0 + a1) + (a2 + a3);                                         \
    }

    if (mode < 2) {
        // ---- self-zero pkt_st through the L2 path (kills stale tags) ----
        const int gid = rank * SL + rl;               // 0..8191
        #pragma unroll
        for (int z = 0; z < 4; ++z)
            pkt_st[(size_t)z * 8192 + gid] = 0;       // 4*8192 = 32768 u64
        if (!bar_wait(&ctrl[3], rl)) return;
        const bool do_inv = (mode == 1);

        // ---- L2-mode main loop: tagged-store, 1-round-trip poll ----
        for (int t = 1; t <= TT; ++t) {
            const int want = t;
            int xi_nxt = xi;
            if (want < TT) xi_nxt = x_idx[want];
            const float xh0 = W_xhT[(size_t)xi * H + e0];
            const float xh1 = v1 ? W_xhT[(size_t)xi * H + e1] : 0.f;
            FMA128(a)
            const int slot = want & (PRING - 1);
            // publish: one 8B plain store (tag|payload) -> XCD-0 L2 dirty
            pkt_st[((size_t)slot * HP + row) * 8 + cc] =
                ((u64)(unsigned)want << 32) | (u64)__float_as_uint(a);
            asm volatile("" ::: "memory");
            // poll: 8 dwordx4 sc0 loads (64B x 2 elements), ONE waitcnt
            const u64* base0 = pkt_st + ((size_t)slot * HP + e0) * 8;
            const u64* base1 = pkt_st + ((size_t)slot * HP + e1) * 8;
            u32x4 A0, A1, A2, A3, B0, B1, B2, B3;
            const unsigned wtag = (unsigned)want;
            unsigned sweeps = 0;
            for (;;) {
                if (do_inv)
                    asm volatile("buffer_inv sc0" ::: "memory");
                asm volatile(
                    "global_load_dwordx4 %0, %8, off sc0\n\t"
                    "global_load_dwordx4 %1, %8, off offset:16 sc0\n\t"
                    "global_load_dwordx4 %2, %8, off offset:32 sc0\n\t"
                    "global_load_dwordx4 %3, %8, off offset:48 sc0\n\t"
                    "global_load_dwordx4 %4, %9, off sc0\n\t"
                    "global_load_dwordx4 %5, %9, off offset:16 sc0\n\t"
                    "global_load_dwordx4 %6, %9, off offset:32 sc0\n\t"
                    "global_load_dwordx4 %7, %9, off offset:48 sc0\n\t"
                    "s_waitcnt vmcnt(0)"
                    : "=&v"(A0), "=&v"(A1), "=&v"(A2), "=&v"(A3),
                      "=&v"(B0), "=&v"(B1), "=&v"(B2), "=&v"(B3)
                    : "v"(base0), "v"(base1)
                    : "memory");
                bool ok = (A0[1] == wtag) & (A0[3] == wtag) &
                          (A1[1] == wtag) & (A1[3] == wtag) &
                          (A2[1] == wtag) & (A2[3] == wtag) &
                          (A3[1] == wtag) & (A3[3] == wtag) &
                          (B0[1] == wtag) & (B0[3] == wtag) &
                          (B1[1] == wtag) & (B1[3] == wtag) &
                          (B2[1] == wtag) & (B2[3] == wtag) &
                          (B3[1] == wtag) & (B3[3] == wtag);
                if (__all(ok)) break;
                if (++sweeps > POLL_LIMIT) return;   // cohort dead: bail
            }
            // fixed j-order sum => bit-identical across redundant finalizers
            float s0 = xh0 + bi0, s1 = xh1 + bi1;
            s0 += __uint_as_float(A0[0]); s0 += __uint_as_float(A0[2]);
            s0 += __uint_as_float(A1[0]); s0 += __uint_as_float(A1[2]);
            s0 += __uint_as_float(A2[0]); s0 += __uint_as_float(A2[2]);
            s0 += __uint_as_float(A3[0]); s0 += __uint_as_float(A3[2]);
            s1 += __uint_as_float(B0[0]); s1 += __uint_as_float(B0[2]);
            s1 += __uint_as_float(B1[0]); s1 += __uint_as_float(B1[2]);
            s1 += __uint_as_float(B2[0]); s1 += __uint_as_float(B2[2]);
            s1 += __uint_as_float(B3[0]); s1 += __uint_as_float(B3[2]);
            const float h0v = tanhf(s0);
            const float h1v = v1 ? tanhf(s1) : 0.f;
            if (want < TT) {
                sh[rl]      = h0v;
                sh[64 + rl] = h1v;
                asm volatile("s_waitcnt lgkmcnt(0)" ::: "memory");
            }
            if (b == cc) {                   // 8 designated writer waves
                h_all[(size_t)want * H + e0] = h0v;
                if (v1) h_all[(size_t)want * H + e1] = h1v;
            }
            xi = xi_nxt;
        }
    } else {
        // ---- MALL mode: EXACT round-0 proven protocol (14.0 ms) ----
        ll old0 = 0, old1 = 0, old2 = 0, old3 = 0;

#define RSTEP(WANT, SLOT, OLDV)                                               \
    {                                                                         \
        const int want = (WANT);                                              \
        int xi_nxt = xi;                                                      \
        if (want < TT) xi_nxt = x_idx[want];                                  \
        const float xh0 = W_xhT[(size_t)xi * H + e0];                         \
        const float xh1 = v1 ? W_xhT[(size_t)xi * H + e1] : 0.f;              \
        FMA128(a)                                                             \
        const ll ev = (ll)(a * 4294967296.0f);                                \
        __hip_atomic_fetch_add(pkt_at + (SLOT) * HP + row,                    \
                               ((u64)(ev - (OLDV)) << 16) | 1ull,             \
                               __ATOMIC_RELAXED, __HIP_MEMORY_SCOPE_AGENT);   \
        (OLDV) = ev;                                                          \
        asm volatile("" ::: "memory");                                        \
        const unsigned expected = 8u * ((unsigned)(want + 3) >> 2);           \
        u64* q0p = pkt_at + (SLOT) * HP + e0;                                 \
        u64 p0, p1;                                                           \
        unsigned sweeps = 0;                                                  \
        for (;;) {                                                            \
            p0 = __hip_atomic_load(q0p, __ATOMIC_RELAXED,                     \
                                   __HIP_MEMORY_SCOPE_AGENT);                 \
            p1 = __hip_atomic_load(q0p + 64, __ATOMIC_RELAXED,                \
                                   __HIP_MEMORY_SCOPE_AGENT);                 \
            const bool ok = ((unsigned)(p0 & 0xFFFFull) == expected) &        \
                            ((unsigned)(p1 & 0xFFFFull) == expected);         \
            if (__all(ok)) break;                                             \
            if (++sweeps > POLL_LIMIT) return;                                \
        }                                                                     \
        const float z0 = (float)((double)((ll)p0 >> 16) *                     \
                                 (1.0 / 4294967296.0)) + xh0 + bi0;           \
        const float z1 = (float)((double)((ll)p1 >> 16) *                     \
                                 (1.0 / 4294967296.0)) + xh1 + bi1;           \
        const float h0v = tanhf(z0);                                          \
        const float h1v = v1 ? tanhf(z1) : 0.f;                               \
        if (want < TT) {                                                      \
            sh[rl]      = h0v;                                                \
            sh[64 + rl] = h1v;                                                \
            asm volatile("s_waitcnt lgkmcnt(0)" ::: "memory");                \
        }                                                                     \
        if (b == cc) {                                                        \
            h_all[(size_t)want * H + e0] = h0v;                               \
            if (v1) h_all[(size_t)want * H + e1] = h1v;                       \
        }                                                                     \
        xi = xi_nxt;                                                          \
    }

        for (int tb = 0; tb < TT; tb += PRING) {
            RSTEP(tb + 1, 1, old1)
            RSTEP(tb + 2, 2, old2)
            RSTEP(tb + 3, 3, old3)
            RSTEP(tb + 4, 0, old0)
        }
#undef RSTEP
    }
#undef FMA128

    if (b == cc && rl == 0)
        __hip_atomic_fetch_add(done, 1, __ATOMIC_RELAXED,
                               __HIP_MEMORY_SCOPE_AGENT);
}

// ---------------------------------------------------------------------------
// FALLBACK: proven R3 agent-scope path (15.2ms). Skipped iff the fast cohort
// fully completed (done == 8) and the fast path was attempted (fail == 0).
// ---------------------------------------------------------------------------
#define FB_RING 4
__global__ __launch_bounds__(64) void rnn_fb(
    const int*   __restrict__ x_idx,
    const float* __restrict__ W_xhT,
    const float* __restrict__ W_hh,
    const float* __restrict__ B_h,
    float*       __restrict__ h_all,
    u64*         __restrict__ pkt,     // FB_RING x 16 x 16 x SL
    const int*   __restrict__ fail,
    const int*   __restrict__ done)
{
    if (__hip_atomic_load(fail, __ATOMIC_RELAXED,
                          __HIP_MEMORY_SCOPE_AGENT) == 0 &&
        __hip_atomic_load(done, __ATOMIC_RELAXED,
                          __HIP_MEMORY_SCOPE_AGENT) == 8)
        return;                               // fast path delivered h_all

    const int rl  = threadIdx.x;
    const int b   = blockIdx.x >> 4;
    const int cc  = blockIdx.x & 15;
    const int row = b * SL + rl;
    const int r   = cc * SL + rl;
    const bool rowv = (row < H);
    const bool rv   = (r < H);

    float w[SL];
    const float* wrow = W_hh + (size_t)row * H;
    #pragma unroll
    for (int q = 0; q < SL / 4; ++q) {
        const int k = cc * SL + 4 * q;
        float4 v = make_float4(0.f, 0.f, 0.f, 0.f);
        if (rowv && (k + 3) < H) v = *(const float4*)(wrow + k);
        w[4*q+0] = v.x; w[4*q+1] = v.y; w[4*q+2] = v.z; w[4*q+3] = v.w;
    }
    const float bh = rv ? B_h[r] : 0.f;

    __shared__ float sh[SL];
    sh[rl] = rv ? h_all[r] : 0.f;
    asm volatile("s_waitcnt lgkmcnt(0)" ::: "memory");

    int xi = x_idx[0];
    for (int t = 0; t < TT; ++t) {
        const unsigned want = (unsigned)(t + 1);
        const int slot = (int)(want & (FB_RING - 1));
        int xi_nxt = xi;
        if (t + 1 < TT) xi_nxt = x_idx[t + 1];
        float xh = 0.f;
        if (rv) xh = W_xhT[(size_t)xi * H + r];

        float a0 = 0.f, a1 = 0.f, a2 = 0.f, a3 = 0.f;
        const float4* hb = (const float4*)sh;
        #pragma unroll
        for (int q = 0; q < SL / 4; ++q) {
            const float4 hv4 = hb[q];
            a0 += w[4*q+0] * hv4.x;
            a1 += w[4*q+1] * hv4.y;
            a2 += w[4*q+2] * hv4.z;
            a3 += w[4*q+3] * hv4.w;
        }
        const float a = (a0 + a1) + (a2 + a3);

        __hip_atomic_store(pkt + (((size_t)slot * 16 + b) * 16 + cc) * SL + rl,
                           ((u64)want << 32) | (u64)__float_as_uint(a),
                           __ATOMIC_RELAXED, __HIP_MEMORY_SCOPE_AGENT);

        const u64* base = pkt + ((size_t)slot * 16 + cc) * 16 * SL + rl;
        u64 p[16];
        for (;;) {
            #pragma unroll
            for (int j = 0; j < 16; ++j)
                p[j] = __hip_atomic_load(base + j * SL, __ATOMIC_RELAXED,
                                         __HIP_MEMORY_SCOPE_AGENT);
            bool ok = true;
            #pragma unroll
            for (int j = 0; j < 16; ++j)
                ok &= ((unsigned)(p[j] >> 32) == want);
            if (__all(ok)) break;
        }

        float s = xh + bh;
        #pragma unroll
        for (int j = 0; j < 16; ++j) s += __uint_as_float((unsigned)p[j]);
        const float hv = rv ? tanhf(s) : 0.f;
        if (b == cc && rv) h_all[(size_t)want * H + r] = hv;
        sh[rl] = hv;
        asm volatile("s_waitcnt lgkmcnt(0)" ::: "memory");
        xi = xi_nxt;
    }
}

// ---------------------------------------------------------------------------
__global__ __launch_bounds__(256) void transpose_wxh(
    const float* __restrict__ W_xh, float* __restrict__ W_xhT)
{
    const int idx = blockIdx.x * 256 + threadIdx.x;
    if (idx < NC * H) {
        const int c = idx / H, r = idx % H;
        W_xhT[idx] = W_xh[r * NC + c];
    }
}

__global__ __launch_bounds__(256) void transpose_why(
    const float* __restrict__ W_hy, float* __restrict__ WhyT)
{
    const int idx = blockIdx.x * 256 + threadIdx.x;
    if (idx < NC * H) {
        const int k = idx / NC, n = idx % NC;
        WhyT[idx] = W_hy[n * H + k];
    }
}

__global__ __launch_bounds__(256) void out_gemm(
    const float* __restrict__ h_all,
    const float* __restrict__ WhyT,   // padded by >=16 floats
    float*       __restrict__ out)
{
    __shared__ float hs[TM * H];      // 64000 B
    const int t0 = blockIdx.x * TM;
    const int nt = min(TM, (TT + 1) - t0);

    const float4* src = (const float4*)(h_all + (size_t)t0 * H);
    const int total4 = nt * H / 4;
    for (int i = threadIdx.x; i < total4; i += 256)
        ((float4*)hs)[i] = src[i];
    __syncthreads();

    const int tl = threadIdx.x >> 4;
    const int ng = threadIdx.x & 15;
    if (tl < nt) {
        float acc0 = 0.f, acc1 = 0.f, acc2 = 0.f, acc3 = 0.f, acc4 = 0.f;
        const float* hrow = hs + tl * H;
        #pragma unroll 4
        for (int k = 0; k < H; ++k) {
            const float hv = hrow[k];
            const float* wr = WhyT + k * NC + ng;
            acc0 += hv * wr[0];
            acc1 += hv * wr[16];
            acc2 += hv * wr[32];
            acc3 += hv * wr[48];
            acc4 += hv * wr[64];
        }
        float* orow = out + (size_t)(t0 + tl) * NC + ng;
        orow[0]  = acc0;
        orow[16] = acc1;
        orow[32] = acc2;
        orow[48] = acc3;
        if (ng < 4) orow[64] = acc4;
    }
}

// ---------------------------------------------------------------------------
extern "C" void kernel_launch(void* const* d_in, const int* in_sizes, int n_in,
                              void* d_out, int out_size, void* d_ws, size_t ws_size,
                              hipStream_t stream)
{
    const int*   x_idx = (const int*)  d_in[0];
    const float* h0    = (const float*)d_in[1];
    const float* W_xh  = (const float*)d_in[2];
    const float* W_hh  = (const float*)d_in[3];
    const float* W_hy  = (const float*)d_in[4];
    const float* B_h   = (const float*)d_in[5];
    float* out = (float*)d_out;

    char* ws = (char*)d_ws;
    size_t off = 0;
    auto take = [&](size_t bytes) {
        void* p = ws + off;
        off = (off + bytes + 255) & ~(size_t)255;
        return p;
    };
    float* h_all  = (float*)take((size_t)(TT + 1) * H * sizeof(float));
    float* WhyT   = (float*)take((size_t)(NC * H + 32) * sizeof(float));
    float* W_xhT  = (float*)take((size_t)(NC * H) * sizeof(float));
    const size_t fb_bytes = (size_t)FB_RING * 16 * 16 * SL * sizeof(u64);
    u64*   pkt_fb = (u64*)take(fb_bytes);
    int*   fail   = (int*)take(64);
    int*   done   = (int*)take(64);
    int*   ctrl   = (int*)take(256);       // own cache lines
    u64*   probe  = (u64*)take(256);       // own cache line (may go L2-dirty)
    const size_t at_bytes = (size_t)PRING * HP * sizeof(u64);       // 32 KB
    u64*   pkt_at = (u64*)take(at_bytes);
    const size_t st_bytes = (size_t)PRING * HP * 8 * sizeof(u64);   // 256 KB
    u64*   pkt_st = (u64*)take(st_bytes);
    const size_t need_fast = off;

    hipMemcpyAsync(h_all, h0, H * sizeof(float),
                   hipMemcpyDeviceToDevice, stream);
    transpose_wxh<<<(NC * H + 255) / 256, 256, 0, stream>>>(W_xh, W_xhT);
    transpose_why<<<(NC * H + 255) / 256, 256, 0, stream>>>(W_hy, WhyT);

    hipMemsetAsync(pkt_fb, 0, fb_bytes, stream);
    hipMemsetAsync(done, 0, 64, stream);
    if (ws_size >= need_fast) {
        hipMemsetAsync(pkt_at, 0, at_bytes, stream);
        hipMemsetAsync(ctrl, 0, 256, stream);
        hipMemsetAsync(probe, 0, 256, stream);
        hipMemsetAsync(fail, 0, 64, stream);
        rnn_fast<<<GRID_FAST, SL, 0, stream>>>(x_idx, W_xhT, W_hh, B_h,
                                               h_all, pkt_at, pkt_st,
                                               ctrl, probe, done);
    } else {
        hipMemsetAsync(fail, 1, 4, stream);    // force fallback
    }
    rnn_fb<<<256, SL, 0, stream>>>(x_idx, W_xhT, W_hh, B_h,
                                   h_all, pkt_fb, fail, done);
    out_gemm<<<(TT + 1 + TM - 1) / TM, 256, 0, stream>>>(h_all, WhyT, out);
}

// Round 5
// 29476.221 us; speedup vs baseline: 1.0850x; 1.0231x over previous
//
#include <hip/hip_runtime.h>
#include <hip/hip_bf16.h>

#define H      1000          // hidden dim
#define HP     1024          // padded hidden (packet elements)
#define TT     8192          // seq len
#define NC     68            // num chars
#define SL     64            // wave size
#define NWAVE  128           // 16 row slices x 8 col chunks
#define PRING  4             // packet ring slots
#define POLL_LIMIT 32768u    // sweeps before declaring the fast path dead
#define PF_LIMIT   8192u     // preflight inv+load probe sweeps
#define BAR_LIMIT  16384u    // barrier spin limit (agent loads)
#define TM     16            // t-tile for output gemm
#define GRID_FAST 2048       // oversubscribed launch; cohort self-assembles on XCD 0
#define PF_MAGIC 0x1DEADBEEFull

typedef unsigned long long u64;
typedef long long ll;
typedef unsigned u32x4 __attribute__((ext_vector_type(4)));

// ---------------------------------------------------------------------------
// FAST PATH v5: round-3's PROVEN visibility mechanism + round-4's batched poll.
//
// Evidence ledger:
//   r3: plain stores + {buffer_inv sc0 + PLAIN loads} completed with
//       WRITE=32MB/FETCH=6.7MB (all packet traffic inside XCD-0's L2).
//       Slow only because 16 volatile loads serialized 16 vmcnt(0) waits.
//   r4: batched loads but with sc0 flags -> WRITE=556MB/FETCH=262MB: sc0
//       LOADS force dirty-L2 writeback + MALL refetch on gfx950. REMOVED.
//
// v5 poll: buffer_inv sc0 (per-CU L1 invalidate, L2 untouched) + 8 PLAIN
// global_load_dwordx4 + ONE s_waitcnt vmcnt(0). Element-major packets
// pkt[slot][element][producer]: each element's 8 (payload|tag) u64s are 64B
// contiguous, so a sweep is one pipelined L2 round trip.
//
// Preflight: prime L1 with the stale probe line -> barrier -> rank0
// plain-stores PF_MAGIC -> bounded {inv + plain load} poll. Waves that fail
// flag ctrl[4]; consensus:
//   all ok  => MODE INV: the r3-proven L2 protocol with the batched poll
//   else    => MODE MALL: EXACT round-0 proven protocol (14.0 ms)
//
// Tags: producer (b,cc) lane rl stores ((want<<32)|f32bits(partial)) to
// pkt[slot][row][cc] (one 8B store, write-through L1 -> L2 dirty). Consumer
// breaks when all 16 tags (8 producers x 2 elements) == want; payloads ride
// in the same 8B words (halves of one >=16B L2 access are consistent). Sum
// in fixed j-order => bit-identical across the 16 redundant finalizers.
// Self-zero of pkt through the L2 path kills cross-run stale tags.
//
// Ring safety (PRING=4): a producer storing @want+4 completed its poll
// @want+3, which transitively spans ALL 16 slices at @want+2, so no poller
// of `want` can observe a later ring generation. Tag equality is exact.
//
// Liveness: every spin (barriers, preflight, polls) is bounded; any overrun
// => wave returns; `done` stays < 8 and the proven R3 fallback recomputes
// ALL of h_all. Participants never depend on non-participants. No hang.
// ---------------------------------------------------------------------------

__device__ __forceinline__ bool bar_wait(int* ctr, int rl)
{
    // drain own vm ops so everything published is complete before arrival
    asm volatile("s_waitcnt vmcnt(0)" ::: "memory");
    if (rl == 0)
        __hip_atomic_fetch_add(ctr, 1, __ATOMIC_RELAXED,
                               __HIP_MEMORY_SCOPE_AGENT);
    unsigned n = 0;
    while (__hip_atomic_load(ctr, __ATOMIC_RELAXED,
                             __HIP_MEMORY_SCOPE_AGENT) < NWAVE) {
        if (++n > BAR_LIMIT) return false;
    }
    return true;
}

__global__ __launch_bounds__(64, 1) void rnn_fast(
    const int*   __restrict__ x_idx,
    const float* __restrict__ W_xhT,   // NC x H
    const float* __restrict__ W_hh,
    const float* __restrict__ B_h,
    float*       __restrict__ h_all,   // (TT+1) x H
    u64*         __restrict__ pkt_at,  // [PRING][HP]        (MALL mode, zeroed)
    u64*         __restrict__ pkt_st,  // [PRING][HP][8]     (INV mode)
    int*         __restrict__ ctrl,    // [0]=claim [1..3]=bars [4]=failINV
    u64*         __restrict__ probe,   // preflight line (own 256B region)
    int*         __restrict__ done)    // completion counter, pre-zeroed
{
    // --- cohort self-assembly on XCD 0 ---
    unsigned xcc;
    asm volatile("s_getreg_b32 %0, hwreg(HW_REG_XCC_ID)" : "=s"(xcc));
    if ((xcc & 7u) != 0u) return;

    const int rl = threadIdx.x;
    int rank = 0;
    if (rl == 0)
        rank = __hip_atomic_fetch_add(&ctrl[0], 1, __ATOMIC_RELAXED,
                                      __HIP_MEMORY_SCOPE_AGENT);
    rank = __builtin_amdgcn_readfirstlane(rank);
    if (rank >= NWAVE) return;

    // --- preflight: prime L1 with the (stale, pre-zeroed) probe line ---
    {
        u64 primed;
        asm volatile(
            "global_load_dwordx2 %0, %1, off\n\t"
            "s_waitcnt vmcnt(0)"
            : "=&v"(primed) : "v"(probe) : "memory");
        asm volatile("" :: "v"(primed));          // keep the prime alive
    }
    if (!bar_wait(&ctrl[1], rl)) return;

    if (rank == 0 && rl == 0)
        *probe = PF_MAGIC;                        // plain store -> L2 dirty
    asm volatile("s_waitcnt vmcnt(0)" ::: "memory");

    // --- preflight poll: {buffer_inv sc0 + PLAIN load} (r3-proven combo) ---
    bool okI = false;
    {
        u64 pv = 0;
        for (unsigned n = 0; n < PF_LIMIT; ++n) {
            asm volatile(
                "buffer_inv sc0\n\t"
                "global_load_dwordx2 %0, %1, off\n\t"
                "s_waitcnt vmcnt(0)"
                : "=&v"(pv) : "v"(probe) : "memory");
            if (pv == (u64)PF_MAGIC) { okI = true; break; }
        }
    }
    if (!okI && rl == 0)
        __hip_atomic_fetch_add(&ctrl[4], 1, __ATOMIC_RELAXED,
                               __HIP_MEMORY_SCOPE_AGENT);
    if (!bar_wait(&ctrl[2], rl)) return;
    const bool modeINV =
        (__hip_atomic_load(&ctrl[4], __ATOMIC_RELAXED,
                           __HIP_MEMORY_SCOPE_AGENT) == 0);

    // --- common setup ---
    const int b  = rank >> 3;                 // row slice 0..15
    const int cc = rank & 7;                  // col chunk 0..7
    const int row = b * SL + rl;              // producer row (<= 1023)
    const int e0  = cc * 128 + rl;            // consumer elements (e0 <= 959)
    const int e1  = e0 + 64;                  // (e1 <= 1023)
    const bool rowv = (row < H);
    const bool v1   = (e1 < H);

    float w[128];
    const float* wrow = W_hh + (size_t)row * H;
    #pragma unroll
    for (int q = 0; q < 32; ++q) {
        const int k = cc * 128 + 4 * q;
        float4 v = make_float4(0.f, 0.f, 0.f, 0.f);
        if (rowv && (k + 3) < H) v = *(const float4*)(wrow + k);
        w[4*q+0] = v.x; w[4*q+1] = v.y; w[4*q+2] = v.z; w[4*q+3] = v.w;
    }
    const float bi0 = B_h[e0];
    const float bi1 = v1 ? B_h[e1] : 0.f;

    __shared__ float sh[128];                 // my h-chunk
    sh[rl]      = h_all[e0];
    sh[64 + rl] = v1 ? h_all[e1] : 0.f;
    asm volatile("s_waitcnt lgkmcnt(0)" ::: "memory");

    int xi = x_idx[0];

#define FMA128(AOUT)                                                          \
    float AOUT;                                                               \
    {                                                                         \
        float a0 = 0.f, a1 = 0.f, a2 = 0.f, a3 = 0.f;                         \
        const float4* hb = (const float4*)sh;                                 \
        _Pragma("unroll")                                                     \
        for (int q = 0; q < 32; ++q) {                                        \
            const float4 hv4 = hb[q];                                         \
            a0 += w[4*q+0] * hv4.x;                                           \
            a1 += w[4*q+1] * hv4.y;                                           \
            a2 += w[4*q+2] * hv4.z;                                           \
            a3 += w[4*q+3] * hv4.w;                                           \
        }                                                                     \
        AOUT = (a0 + a1) + (a2 + a3);                                         \
    }

    if (modeINV) {
        // ---- self-zero pkt_st through the L2 path (kills stale tags) ----
        const int gid = rank * SL + rl;               // 0..8191
        #pragma unroll
        for (int z = 0; z < 4; ++z)
            pkt_st[(size_t)z * 8192 + gid] = 0;       // 4*8192 = 32768 u64
        if (!bar_wait(&ctrl[3], rl)) return;

        // ---- INV-mode main loop: tagged-store, batched 1-trip poll ----
        for (int t = 1; t <= TT; ++t) {
            const int want = t;
            int xi_nxt = xi;
            if (want < TT) xi_nxt = x_idx[want];
            const float xh0 = W_xhT[(size_t)xi * H + e0];
            const float xh1 = v1 ? W_xhT[(size_t)xi * H + e1] : 0.f;
            FMA128(a)
            const int slot = want & (PRING - 1);
            // publish: one 8B plain store (tag|payload) -> XCD-0 L2 dirty
            pkt_st[((size_t)slot * HP + row) * 8 + cc] =
                ((u64)(unsigned)want << 32) | (u64)__float_as_uint(a);
            asm volatile("" ::: "memory");
            // poll: inv + 8 PLAIN dwordx4 loads (64B x 2 elems), ONE waitcnt
            const u64* base0 = pkt_st + ((size_t)slot * HP + e0) * 8;
            const u64* base1 = pkt_st + ((size_t)slot * HP + e1) * 8;
            u32x4 A0, A1, A2, A3, B0, B1, B2, B3;
            const unsigned wtag = (unsigned)want;
            unsigned sweeps = 0;
            for (;;) {
                asm volatile("buffer_inv sc0" ::: "memory");
                asm volatile(
                    "global_load_dwordx4 %0, %8, off\n\t"
                    "global_load_dwordx4 %1, %8, off offset:16\n\t"
                    "global_load_dwordx4 %2, %8, off offset:32\n\t"
                    "global_load_dwordx4 %3, %8, off offset:48\n\t"
                    "global_load_dwordx4 %4, %9, off\n\t"
                    "global_load_dwordx4 %5, %9, off offset:16\n\t"
                    "global_load_dwordx4 %6, %9, off offset:32\n\t"
                    "global_load_dwordx4 %7, %9, off offset:48\n\t"
                    "s_waitcnt vmcnt(0)"
                    : "=&v"(A0), "=&v"(A1), "=&v"(A2), "=&v"(A3),
                      "=&v"(B0), "=&v"(B1), "=&v"(B2), "=&v"(B3)
                    : "v"(base0), "v"(base1)
                    : "memory");
                bool ok = (A0[1] == wtag) & (A0[3] == wtag) &
                          (A1[1] == wtag) & (A1[3] == wtag) &
                          (A2[1] == wtag) & (A2[3] == wtag) &
                          (A3[1] == wtag) & (A3[3] == wtag) &
                          (B0[1] == wtag) & (B0[3] == wtag) &
                          (B1[1] == wtag) & (B1[3] == wtag) &
                          (B2[1] == wtag) & (B2[3] == wtag) &
                          (B3[1] == wtag) & (B3[3] == wtag);
                if (__all(ok)) break;
                if (++sweeps > POLL_LIMIT) return;   // cohort dead: bail
            }
            // fixed j-order sum => bit-identical across redundant finalizers
            float s0 = xh0 + bi0, s1 = xh1 + bi1;
            s0 += __uint_as_float(A0[0]); s0 += __uint_as_float(A0[2]);
            s0 += __uint_as_float(A1[0]); s0 += __uint_as_float(A1[2]);
            s0 += __uint_as_float(A2[0]); s0 += __uint_as_float(A2[2]);
            s0 += __uint_as_float(A3[0]); s0 += __uint_as_float(A3[2]);
            s1 += __uint_as_float(B0[0]); s1 += __uint_as_float(B0[2]);
            s1 += __uint_as_float(B1[0]); s1 += __uint_as_float(B1[2]);
            s1 += __uint_as_float(B2[0]); s1 += __uint_as_float(B2[2]);
            s1 += __uint_as_float(B3[0]); s1 += __uint_as_float(B3[2]);
            const float h0v = tanhf(s0);
            const float h1v = v1 ? tanhf(s1) : 0.f;
            if (want < TT) {
                sh[rl]      = h0v;
                sh[64 + rl] = h1v;
                asm volatile("s_waitcnt lgkmcnt(0)" ::: "memory");
            }
            if (b == cc) {                   // 8 designated writer waves
                h_all[(size_t)want * H + e0] = h0v;
                if (v1) h_all[(size_t)want * H + e1] = h1v;
            }
            xi = xi_nxt;
        }
    } else {
        // ---- MALL mode: EXACT round-0 proven protocol (14.0 ms) ----
        ll old0 = 0, old1 = 0, old2 = 0, old3 = 0;

#define RSTEP(WANT, SLOT, OLDV)                                               \
    {                                                                         \
        const int want = (WANT);                                              \
        int xi_nxt = xi;                                                      \
        if (want < TT) xi_nxt = x_idx[want];                                  \
        const float xh0 = W_xhT[(size_t)xi * H + e0];                         \
        const float xh1 = v1 ? W_xhT[(size_t)xi * H + e1] : 0.f;              \
        FMA128(a)                                                             \
        const ll ev = (ll)(a * 4294967296.0f);                                \
        __hip_atomic_fetch_add(pkt_at + (SLOT) * HP + row,                    \
                               ((u64)(ev - (OLDV)) << 16) | 1ull,             \
                               __ATOMIC_RELAXED, __HIP_MEMORY_SCOPE_AGENT);   \
        (OLDV) = ev;                                                          \
        asm volatile("" ::: "memory");                                        \
        const unsigned expected = 8u * ((unsigned)(want + 3) >> 2);           \
        u64* q0p = pkt_at + (SLOT) * HP + e0;                                 \
        u64 p0, p1;                                                           \
        unsigned sweeps = 0;                                                  \
        for (;;) {                                                            \
            p0 = __hip_atomic_load(q0p, __ATOMIC_RELAXED,                     \
                                   __HIP_MEMORY_SCOPE_AGENT);                 \
            p1 = __hip_atomic_load(q0p + 64, __ATOMIC_RELAXED,                \
                                   __HIP_MEMORY_SCOPE_AGENT);                 \
            const bool ok = ((unsigned)(p0 & 0xFFFFull) == expected) &        \
                            ((unsigned)(p1 & 0xFFFFull) == expected);         \
            if (__all(ok)) break;                                             \
            if (++sweeps > POLL_LIMIT) return;                                \
        }                                                                     \
        const float z0 = (float)((double)((ll)p0 >> 16) *                     \
                                 (1.0 / 4294967296.0)) + xh0 + bi0;           \
        const float z1 = (float)((double)((ll)p1 >> 16) *                     \
                                 (1.0 / 4294967296.0)) + xh1 + bi1;           \
        const float h0v = tanhf(z0);                                          \
        const float h1v = v1 ? tanhf(z1) : 0.f;                               \
        if (want < TT) {                                                      \
            sh[rl]      = h0v;                                                \
            sh[64 + rl] = h1v;                                                \
            asm volatile("s_waitcnt lgkmcnt(0)" ::: "memory");                \
        }                                                                     \
        if (b == cc) {                                                        \
            h_all[(size_t)want * H + e0] = h0v;                               \
            if (v1) h_all[(size_t)want * H + e1] = h1v;                       \
        }                                                                     \
        xi = xi_nxt;                                                          \
    }

        for (int tb = 0; tb < TT; tb += PRING) {
            RSTEP(tb + 1, 1, old1)
            RSTEP(tb + 2, 2, old2)
            RSTEP(tb + 3, 3, old3)
            RSTEP(tb + 4, 0, old0)
        }
#undef RSTEP
    }
#undef FMA128

    if (b == cc && rl == 0)
        __hip_atomic_fetch_add(done, 1, __ATOMIC_RELAXED,
                               __HIP_MEMORY_SCOPE_AGENT);
}

// ---------------------------------------------------------------------------
// FALLBACK: proven R3 agent-scope path (15.2ms). Skipped iff the fast cohort
// fully completed (done == 8) and the fast path was attempted (fail == 0).
// ---------------------------------------------------------------------------
#define FB_RING 4
__global__ __launch_bounds__(64) void rnn_fb(
    const int*   __restrict__ x_idx,
    const float* __restrict__ W_xhT,
    const float* __restrict__ W_hh,
    const float* __restrict__ B_h,
    float*       __restrict__ h_all,
    u64*         __restrict__ pkt,     // FB_RING x 16 x 16 x SL
    const int*   __restrict__ fail,
    const int*   __restrict__ done)
{
    if (__hip_atomic_load(fail, __ATOMIC_RELAXED,
                          __HIP_MEMORY_SCOPE_AGENT) == 0 &&
        __hip_atomic_load(done, __ATOMIC_RELAXED,
                          __HIP_MEMORY_SCOPE_AGENT) == 8)
        return;                               // fast path delivered h_all

    const int rl  = threadIdx.x;
    const int b   = blockIdx.x >> 4;
    const int cc  = blockIdx.x & 15;
    const int row = b * SL + rl;
    const int r   = cc * SL + rl;
    const bool rowv = (row < H);
    const bool rv   = (r < H);

    float w[SL];
    const float* wrow = W_hh + (size_t)row * H;
    #pragma unroll
    for (int q = 0; q < SL / 4; ++q) {
        const int k = cc * SL + 4 * q;
        float4 v = make_float4(0.f, 0.f, 0.f, 0.f);
        if (rowv && (k + 3) < H) v = *(const float4*)(wrow + k);
        w[4*q+0] = v.x; w[4*q+1] = v.y; w[4*q+2] = v.z; w[4*q+3] = v.w;
    }
    const float bh = rv ? B_h[r] : 0.f;

    __shared__ float sh[SL];
    sh[rl] = rv ? h_all[r] : 0.f;
    asm volatile("s_waitcnt lgkmcnt(0)" ::: "memory");

    int xi = x_idx[0];
    for (int t = 0; t < TT; ++t) {
        const unsigned want = (unsigned)(t + 1);
        const int slot = (int)(want & (FB_RING - 1));
        int xi_nxt = xi;
        if (t + 1 < TT) xi_nxt = x_idx[t + 1];
        float xh = 0.f;
        if (rv) xh = W_xhT[(size_t)xi * H + r];

        float a0 = 0.f, a1 = 0.f, a2 = 0.f, a3 = 0.f;
        const float4* hb = (const float4*)sh;
        #pragma unroll
        for (int q = 0; q < SL / 4; ++q) {
            const float4 hv4 = hb[q];
            a0 += w[4*q+0] * hv4.x;
            a1 += w[4*q+1] * hv4.y;
            a2 += w[4*q+2] * hv4.z;
            a3 += w[4*q+3] * hv4.w;
        }
        const float a = (a0 + a1) + (a2 + a3);

        __hip_atomic_store(pkt + (((size_t)slot * 16 + b) * 16 + cc) * SL + rl,
                           ((u64)want << 32) | (u64)__float_as_uint(a),
                           __ATOMIC_RELAXED, __HIP_MEMORY_SCOPE_AGENT);

        const u64* base = pkt + ((size_t)slot * 16 + cc) * 16 * SL + rl;
        u64 p[16];
        for (;;) {
            #pragma unroll
            for (int j = 0; j < 16; ++j)
                p[j] = __hip_atomic_load(base + j * SL, __ATOMIC_RELAXED,
                                         __HIP_MEMORY_SCOPE_AGENT);
            bool ok = true;
            #pragma unroll
            for (int j = 0; j < 16; ++j)
                ok &= ((unsigned)(p[j] >> 32) == want);
            if (__all(ok)) break;
        }

        float s = xh + bh;
        #pragma unroll
        for (int j = 0; j < 16; ++j) s += __uint_as_float((unsigned)p[j]);
        const float hv = rv ? tanhf(s) : 0.f;
        if (b == cc && rv) h_all[(size_t)want * H + r] = hv;
        sh[rl] = hv;
        asm volatile("s_waitcnt lgkmcnt(0)" ::: "memory");
        xi = xi_nxt;
    }
}

// ---------------------------------------------------------------------------
__global__ __launch_bounds__(256) void transpose_wxh(
    const float* __restrict__ W_xh, float* __restrict__ W_xhT)
{
    const int idx = blockIdx.x * 256 + threadIdx.x;
    if (idx < NC * H) {
        const int c = idx / H, r = idx % H;
        W_xhT[idx] = W_xh[r * NC + c];
    }
}

__global__ __launch_bounds__(256) void transpose_why(
    const float* __restrict__ W_hy, float* __restrict__ WhyT)
{
    const int idx = blockIdx.x * 256 + threadIdx.x;
    if (idx < NC * H) {
        const int k = idx / NC, n = idx % NC;
        WhyT[idx] = W_hy[n * H + k];
    }
}

__global__ __launch_bounds__(256) void out_gemm(
    const float* __restrict__ h_all,
    const float* __restrict__ WhyT,   // padded by >=16 floats
    float*       __restrict__ out)
{
    __shared__ float hs[TM * H];      // 64000 B
    const int t0 = blockIdx.x * TM;
    const int nt = min(TM, (TT + 1) - t0);

    const float4* src = (const float4*)(h_all + (size_t)t0 * H);
    const int total4 = nt * H / 4;
    for (int i = threadIdx.x; i < total4; i += 256)
        ((float4*)hs)[i] = src[i];
    __syncthreads();

    const int tl = threadIdx.x >> 4;
    const int ng = threadIdx.x & 15;
    if (tl < nt) {
        float acc0 = 0.f, acc1 = 0.f, acc2 = 0.f, acc3 = 0.f, acc4 = 0.f;
        const float* hrow = hs + tl * H;
        #pragma unroll 4
        for (int k = 0; k < H; ++k) {
            const float hv = hrow[k];
            const float* wr = WhyT + k * NC + ng;
            acc0 += hv * wr[0];
            acc1 += hv * wr[16];
            acc2 += hv * wr[32];
            acc3 += hv * wr[48];
            acc4 += hv * wr[64];
        }
        float* orow = out + (size_t)(t0 + tl) * NC + ng;
        orow[0]  = acc0;
        orow[16] = acc1;
        orow[32] = acc2;
        orow[48] = acc3;
        if (ng < 4) orow[64] = acc4;
    }
}

// ---------------------------------------------------------------------------
extern "C" void kernel_launch(void* const* d_in, const int* in_sizes, int n_in,
                              void* d_out, int out_size, void* d_ws, size_t ws_size,
                              hipStream_t stream)
{
    const int*   x_idx = (const int*)  d_in[0];
    const float* h0    = (const float*)d_in[1];
    const float* W_xh  = (const float*)d_in[2];
    const float* W_hh  = (const float*)d_in[3];
    const float* W_hy  = (const float*)d_in[4];
    const float* B_h   = (const float*)d_in[5];
    float* out = (float*)d_out;

    char* ws = (char*)d_ws;
    size_t off = 0;
    auto take = [&](size_t bytes) {
        void* p = ws + off;
        off = (off + bytes + 255) & ~(size_t)255;
        return p;
    };
    float* h_all  = (float*)take((size_t)(TT + 1) * H * sizeof(float));
    float* WhyT   = (float*)take((size_t)(NC * H + 32) * sizeof(float));
    float* W_xhT  = (float*)take((size_t)(NC * H) * sizeof(float));
    const size_t fb_bytes = (size_t)FB_RING * 16 * 16 * SL * sizeof(u64);
    u64*   pkt_fb = (u64*)take(fb_bytes);
    int*   fail   = (int*)take(64);
    int*   done   = (int*)take(64);
    int*   ctrl   = (int*)take(256);       // own cache lines
    u64*   probe  = (u64*)take(256);       // own cache line (may go L2-dirty)
    const size_t at_bytes = (size_t)PRING * HP * sizeof(u64);       // 32 KB
    u64*   pkt_at = (u64*)take(at_bytes);
    const size_t st_bytes = (size_t)PRING * HP * 8 * sizeof(u64);   // 256 KB
    u64*   pkt_st = (u64*)take(st_bytes);
    const size_t need_fast = off;

    hipMemcpyAsync(h_all, h0, H * sizeof(float),
                   hipMemcpyDeviceToDevice, stream);
    transpose_wxh<<<(NC * H + 255) / 256, 256, 0, stream>>>(W_xh, W_xhT);
    transpose_why<<<(NC * H + 255) / 256, 256, 0, stream>>>(W_hy, WhyT);

    hipMemsetAsync(pkt_fb, 0, fb_bytes, stream);
    hipMemsetAsync(done, 0, 64, stream);
    if (ws_size >= need_fast) {
        hipMemsetAsync(pkt_at, 0, at_bytes, stream);
        hipMemsetAsync(ctrl, 0, 256, stream);
        hipMemsetAsync(probe, 0, 256, stream);
        hipMemsetAsync(fail, 0, 64, stream);
        rnn_fast<<<GRID_FAST, SL, 0, stream>>>(x_idx, W_xhT, W_hh, B_h,
                                               h_all, pkt_at, pkt_st,
                                               ctrl, probe, done);
    } else {
        hipMemsetAsync(fail, 1, 4, stream);    // force fallback
    }
    rnn_fb<<<256, SL, 0, stream>>>(x_idx, W_xhT, W_hh, B_h,
                                   h_all, pkt_fb, fail, done);
    out_gemm<<<(TT + 1 + TM - 1) / TM, 256, 0, stream>>>(h_all, WhyT, out);
}

// Round 6
// 29382.349 us; speedup vs baseline: 1.0885x; 1.0032x over previous
//
#include <hip/hip_runtime.h>
#include <hip/hip_bf16.h>

#define H      1000          // hidden dim
#define HP     1024          // padded hidden (packet elements)
#define TT     8192          // seq len
#define NC     68            // num chars
#define SL     64            // wave size
#define NWAVE  128           // 16 row slices x 8 col chunks
#define PRING  4             // packet ring slots
#define POLL_LIMIT 32768u    // sweeps before declaring the fast path dead
#define PF_LIMIT   8192u     // preflight inv+load probe sweeps
#define BAR_LIMIT  16384u    // barrier spin limit (agent loads)
#define TM     16            // t-tile for output gemm
#define GRID_FAST 2048       // oversubscribed launch; cohort self-assembles on XCD 0
#define PF_MAGIC 0x1DEADBEEFull

typedef unsigned long long u64;
typedef long long ll;

// ---------------------------------------------------------------------------
// FAST PATH v6: r3-proven L2-resident traffic + one-round-trip batched poll.
//
// Evidence ledger:
//   r3: COALESCED 512B/wave packet stores + {buffer_inv sc0 + plain loads}:
//       WRITE=32MB/FETCH=6.7MB -> all packet traffic L2-resident. Slow only
//       because 16 volatile loads serialized 16 vmcnt(0) round trips.
//   r4: element-major layout (8B store fragments of 64 distinct lines) ->
//       WRITE=556MB/FETCH=262MB. r5: same WITHOUT sc0 on loads -> identical.
//       => sc0-load theory FALSIFIED; SCATTERED PARTIAL-LINE STORES are what
//       pushes the protocol to HBM (write-through/no-allocate on partial-line
//       L2 miss). Full-line coalesced stores write-allocate and stay in L2.
//
// v6 layout pkt[slot][group e>>6][producer j][r=e&63] gives BOTH:
//   producer (b,cc) lane rl stores ((want<<32)|f32bits(a)) at
//   ((slot*16+b)*8+cc)*64+rl -> the wave's 64 stores are 512B CONTIGUOUS
//   (r3's proven full-line store pattern);
//   consumer of e0=cc*128+rl polls 8 tags at base ((slot*16+2cc)*8+j)*64+rl,
//   j-stride 512B -> 16 plain global_load_dwordx2 from 2 base registers with
//   immediate offsets 0..3584, ONE asm block, ONE s_waitcnt vmcnt(0),
//   preceded by buffer_inv sc0 (r3-proven visibility): one pipelined L2
//   round trip per sweep instead of 16 serialized ones.
//
// Preflight gates INV mode vs the round-0-proven MALL protocol: prime L1
// with the stale probe line -> barrier -> rank0 plain-stores PF_MAGIC ->
// bounded {inv + plain load} poll; any failure => MALL mode (14.0 ms).
//
// Correctness: tags are absolute (want), payload rides in the same 8B word
// (halves of one 8B access are consistent); consumer breaks when all 16
// tags == want; fixed j-order sum => bit-identical across the 16 redundant
// finalizers. Self-zero of pkt through the L2 path kills cross-run stale
// tags. Ring safety (PRING=4): a producer storing @want+4 completed its
// poll @want+3, which transitively spans ALL 16 slices at @want+2, so no
// poller of `want` can observe a later ring generation.
//
// Liveness: every spin (barriers, preflight, polls) is bounded; any overrun
// => wave returns; `done` stays < 8 and the proven R3 fallback recomputes
// ALL of h_all. Participants never depend on non-participants. No hang.
// ---------------------------------------------------------------------------

__device__ __forceinline__ bool bar_wait(int* ctr, int rl)
{
    // drain own vm ops so everything published is complete before arrival
    asm volatile("s_waitcnt vmcnt(0)" ::: "memory");
    if (rl == 0)
        __hip_atomic_fetch_add(ctr, 1, __ATOMIC_RELAXED,
                               __HIP_MEMORY_SCOPE_AGENT);
    unsigned n = 0;
    while (__hip_atomic_load(ctr, __ATOMIC_RELAXED,
                             __HIP_MEMORY_SCOPE_AGENT) < NWAVE) {
        if (++n > BAR_LIMIT) return false;
    }
    return true;
}

__global__ __launch_bounds__(64, 1) void rnn_fast(
    const int*   __restrict__ x_idx,
    const float* __restrict__ W_xhT,   // NC x H
    const float* __restrict__ W_hh,
    const float* __restrict__ B_h,
    float*       __restrict__ h_all,   // (TT+1) x H
    u64*         __restrict__ pkt_at,  // [PRING][HP]          (MALL mode, zeroed)
    u64*         __restrict__ pkt_st,  // [PRING][16][8][64]   (INV mode)
    int*         __restrict__ ctrl,    // [0]=claim [1..3]=bars [4]=failINV
    u64*         __restrict__ probe,   // preflight line (own 256B region)
    int*         __restrict__ done)    // completion counter, pre-zeroed
{
    // --- cohort self-assembly on XCD 0 ---
    unsigned xcc;
    asm volatile("s_getreg_b32 %0, hwreg(HW_REG_XCC_ID)" : "=s"(xcc));
    if ((xcc & 7u) != 0u) return;

    const int rl = threadIdx.x;
    int rank = 0;
    if (rl == 0)
        rank = __hip_atomic_fetch_add(&ctrl[0], 1, __ATOMIC_RELAXED,
                                      __HIP_MEMORY_SCOPE_AGENT);
    rank = __builtin_amdgcn_readfirstlane(rank);
    if (rank >= NWAVE) return;

    // --- preflight: prime L1 with the (stale, pre-zeroed) probe line ---
    {
        u64 primed;
        asm volatile(
            "global_load_dwordx2 %0, %1, off\n\t"
            "s_waitcnt vmcnt(0)"
            : "=&v"(primed) : "v"(probe) : "memory");
        asm volatile("" :: "v"(primed));          // keep the prime alive
    }
    if (!bar_wait(&ctrl[1], rl)) return;

    if (rank == 0 && rl == 0)
        *probe = PF_MAGIC;                        // plain store -> L2 dirty
    asm volatile("s_waitcnt vmcnt(0)" ::: "memory");

    // --- preflight poll: {buffer_inv sc0 + PLAIN load} (r3-proven combo) ---
    bool okI = false;
    {
        u64 pv = 0;
        for (unsigned n = 0; n < PF_LIMIT; ++n) {
            asm volatile(
                "buffer_inv sc0\n\t"
                "global_load_dwordx2 %0, %1, off\n\t"
                "s_waitcnt vmcnt(0)"
                : "=&v"(pv) : "v"(probe) : "memory");
            if (pv == (u64)PF_MAGIC) { okI = true; break; }
        }
    }
    if (!okI && rl == 0)
        __hip_atomic_fetch_add(&ctrl[4], 1, __ATOMIC_RELAXED,
                               __HIP_MEMORY_SCOPE_AGENT);
    if (!bar_wait(&ctrl[2], rl)) return;
    const bool modeINV =
        (__hip_atomic_load(&ctrl[4], __ATOMIC_RELAXED,
                           __HIP_MEMORY_SCOPE_AGENT) == 0);

    // --- common setup ---
    const int b  = rank >> 3;                 // row slice 0..15
    const int cc = rank & 7;                  // col chunk 0..7
    const int row = b * SL + rl;              // producer row (<= 1023)
    const int e0  = cc * 128 + rl;            // consumer elements (e0 <= 959)
    const int e1  = e0 + 64;                  // (e1 <= 1023)
    const bool rowv = (row < H);
    const bool v1   = (e1 < H);

    float w[128];
    const float* wrow = W_hh + (size_t)row * H;
    #pragma unroll
    for (int q = 0; q < 32; ++q) {
        const int k = cc * 128 + 4 * q;
        float4 v = make_float4(0.f, 0.f, 0.f, 0.f);
        if (rowv && (k + 3) < H) v = *(const float4*)(wrow + k);
        w[4*q+0] = v.x; w[4*q+1] = v.y; w[4*q+2] = v.z; w[4*q+3] = v.w;
    }
    const float bi0 = B_h[e0];
    const float bi1 = v1 ? B_h[e1] : 0.f;

    __shared__ float sh[128];                 // my h-chunk
    sh[rl]      = h_all[e0];
    sh[64 + rl] = v1 ? h_all[e1] : 0.f;
    asm volatile("s_waitcnt lgkmcnt(0)" ::: "memory");

    int xi = x_idx[0];

#define FMA128(AOUT)                                                          \
    float AOUT;                                                               \
    {                                                                         \
        float a0 = 0.f, a1 = 0.f, a2 = 0.f, a3 = 0.f;                         \
        const float4* hb = (const float4*)sh;                                 \
        _Pragma("unroll")                                                     \
        for (int q = 0; q < 32; ++q) {                                        \
            const float4 hv4 = hb[q];                                         \
            a0 += w[4*q+0] * hv4.x;                                           \
            a1 += w[4*q+1] * hv4.y;                                           \
            a2 += w[4*q+2] * hv4.z;                                           \
            a3 += w[4*q+3] * hv4.w;                                           \
        }                                                                     \
        AOUT = (a0 + a1) + (a2 + a3);                                         \
    }

    if (modeINV) {
        // ---- self-zero pkt_st through the L2 path (kills stale tags) ----
        const int gid = rank * SL + rl;               // 0..8191
        #pragma unroll
        for (int z = 0; z < 4; ++z)
            pkt_st[(size_t)z * 8192 + gid] = 0;       // 4*8192 = 32768 u64
        if (!bar_wait(&ctrl[3], rl)) return;

        // consumer poll bases: group g0=2cc holds e0's row, g1=2cc+1 e1's
        const size_t slot_stride = 16 * 8 * 64;       // u64 per ring slot

        // ---- INV-mode main loop ----
        for (int t = 1; t <= TT; ++t) {
            const int want = t;
            int xi_nxt = xi;
            if (want < TT) xi_nxt = x_idx[want];
            const float xh0 = W_xhT[(size_t)xi * H + e0];
            const float xh1 = v1 ? W_xhT[(size_t)xi * H + e1] : 0.f;
            FMA128(a)
            const int slot = want & (PRING - 1);
            // publish: wave's 64 lanes store 512B CONTIGUOUS (full lines ->
            // L2 write-allocate; the r3-proven L2-resident store pattern)
            pkt_st[slot * slot_stride + (((size_t)b * 8 + cc) * 64) + rl] =
                ((u64)(unsigned)want << 32) | (u64)__float_as_uint(a);
            asm volatile("" ::: "memory");
            // poll: inv + 16 PLAIN dwordx2 loads (2 bases, imm offsets
            // j*512B), ONE s_waitcnt -> one pipelined L2 round trip
            const u64* base0 = pkt_st + slot * slot_stride
                             + ((size_t)(2 * cc)     * 8) * 64 + rl;
            const u64* base1 = pkt_st + slot * slot_stride
                             + ((size_t)(2 * cc + 1) * 8) * 64 + rl;
            u64 p00, p01, p02, p03, p04, p05, p06, p07;
            u64 p10, p11, p12, p13, p14, p15, p16, p17;
            const unsigned wtag = (unsigned)want;
            unsigned sweeps = 0;
            for (;;) {
                asm volatile(
                    "buffer_inv sc0\n\t"
                    "global_load_dwordx2 %0, %16, off\n\t"
                    "global_load_dwordx2 %1, %16, off offset:512\n\t"
                    "global_load_dwordx2 %2, %16, off offset:1024\n\t"
                    "global_load_dwordx2 %3, %16, off offset:1536\n\t"
                    "global_load_dwordx2 %4, %16, off offset:2048\n\t"
                    "global_load_dwordx2 %5, %16, off offset:2560\n\t"
                    "global_load_dwordx2 %6, %16, off offset:3072\n\t"
                    "global_load_dwordx2 %7, %16, off offset:3584\n\t"
                    "global_load_dwordx2 %8, %17, off\n\t"
                    "global_load_dwordx2 %9, %17, off offset:512\n\t"
                    "global_load_dwordx2 %10, %17, off offset:1024\n\t"
                    "global_load_dwordx2 %11, %17, off offset:1536\n\t"
                    "global_load_dwordx2 %12, %17, off offset:2048\n\t"
                    "global_load_dwordx2 %13, %17, off offset:2560\n\t"
                    "global_load_dwordx2 %14, %17, off offset:3072\n\t"
                    "global_load_dwordx2 %15, %17, off offset:3584\n\t"
                    "s_waitcnt vmcnt(0)"
                    : "=&v"(p00), "=&v"(p01), "=&v"(p02), "=&v"(p03),
                      "=&v"(p04), "=&v"(p05), "=&v"(p06), "=&v"(p07),
                      "=&v"(p10), "=&v"(p11), "=&v"(p12), "=&v"(p13),
                      "=&v"(p14), "=&v"(p15), "=&v"(p16), "=&v"(p17)
                    : "v"(base0), "v"(base1)
                    : "memory");
                bool ok = ((unsigned)(p00 >> 32) == wtag) &
                          ((unsigned)(p01 >> 32) == wtag) &
                          ((unsigned)(p02 >> 32) == wtag) &
                          ((unsigned)(p03 >> 32) == wtag) &
                          ((unsigned)(p04 >> 32) == wtag) &
                          ((unsigned)(p05 >> 32) == wtag) &
                          ((unsigned)(p06 >> 32) == wtag) &
                          ((unsigned)(p07 >> 32) == wtag) &
                          ((unsigned)(p10 >> 32) == wtag) &
                          ((unsigned)(p11 >> 32) == wtag) &
                          ((unsigned)(p12 >> 32) == wtag) &
                          ((unsigned)(p13 >> 32) == wtag) &
                          ((unsigned)(p14 >> 32) == wtag) &
                          ((unsigned)(p15 >> 32) == wtag) &
                          ((unsigned)(p16 >> 32) == wtag) &
                          ((unsigned)(p17 >> 32) == wtag);
                if (__all(ok)) break;
                if (++sweeps > POLL_LIMIT) return;   // cohort dead: bail
            }
            // fixed j-order sum => bit-identical across redundant finalizers
            float s0 = xh0 + bi0, s1 = xh1 + bi1;
            s0 += __uint_as_float((unsigned)p00);
            s0 += __uint_as_float((unsigned)p01);
            s0 += __uint_as_float((unsigned)p02);
            s0 += __uint_as_float((unsigned)p03);
            s0 += __uint_as_float((unsigned)p04);
            s0 += __uint_as_float((unsigned)p05);
            s0 += __uint_as_float((unsigned)p06);
            s0 += __uint_as_float((unsigned)p07);
            s1 += __uint_as_float((unsigned)p10);
            s1 += __uint_as_float((unsigned)p11);
            s1 += __uint_as_float((unsigned)p12);
            s1 += __uint_as_float((unsigned)p13);
            s1 += __uint_as_float((unsigned)p14);
            s1 += __uint_as_float((unsigned)p15);
            s1 += __uint_as_float((unsigned)p16);
            s1 += __uint_as_float((unsigned)p17);
            const float h0v = tanhf(s0);
            const float h1v = v1 ? tanhf(s1) : 0.f;
            if (want < TT) {
                sh[rl]      = h0v;
                sh[64 + rl] = h1v;
                asm volatile("s_waitcnt lgkmcnt(0)" ::: "memory");
            }
            if (b == cc) {                   // 8 designated writer waves
                h_all[(size_t)want * H + e0] = h0v;
                if (v1) h_all[(size_t)want * H + e1] = h1v;
            }
            xi = xi_nxt;
        }
    } else {
        // ---- MALL mode: EXACT round-0 proven protocol (14.0 ms) ----
        ll old0 = 0, old1 = 0, old2 = 0, old3 = 0;

#define RSTEP(WANT, SLOT, OLDV)                                               \
    {                                                                         \
        const int want = (WANT);                                              \
        int xi_nxt = xi;                                                      \
        if (want < TT) xi_nxt = x_idx[want];                                  \
        const float xh0 = W_xhT[(size_t)xi * H + e0];                         \
        const float xh1 = v1 ? W_xhT[(size_t)xi * H + e1] : 0.f;              \
        FMA128(a)                                                             \
        const ll ev = (ll)(a * 4294967296.0f);                                \
        __hip_atomic_fetch_add(pkt_at + (SLOT) * HP + row,                    \
                               ((u64)(ev - (OLDV)) << 16) | 1ull,             \
                               __ATOMIC_RELAXED, __HIP_MEMORY_SCOPE_AGENT);   \
        (OLDV) = ev;                                                          \
        asm volatile("" ::: "memory");                                        \
        const unsigned expected = 8u * ((unsigned)(want + 3) >> 2);           \
        u64* q0p = pkt_at + (SLOT) * HP + e0;                                 \
        u64 p0, p1;                                                           \
        unsigned sweeps = 0;                                                  \
        for (;;) {                                                            \
            p0 = __hip_atomic_load(q0p, __ATOMIC_RELAXED,                     \
                                   __HIP_MEMORY_SCOPE_AGENT);                 \
            p1 = __hip_atomic_load(q0p + 64, __ATOMIC_RELAXED,                \
                                   __HIP_MEMORY_SCOPE_AGENT);                 \
            const bool ok = ((unsigned)(p0 & 0xFFFFull) == expected) &        \
                            ((unsigned)(p1 & 0xFFFFull) == expected);         \
            if (__all(ok)) break;                                             \
            if (++sweeps > POLL_LIMIT) return;                                \
        }                                                                     \
        const float z0 = (float)((double)((ll)p0 >> 16) *                     \
                                 (1.0 / 4294967296.0)) + xh0 + bi0;           \
        const float z1 = (float)((double)((ll)p1 >> 16) *                     \
                                 (1.0 / 4294967296.0)) + xh1 + bi1;           \
        const float h0v = tanhf(z0);                                          \
        const float h1v = v1 ? tanhf(z1) : 0.f;                               \
        if (want < TT) {                                                      \
            sh[rl]      = h0v;                                                \
            sh[64 + rl] = h1v;                                                \
            asm volatile("s_waitcnt lgkmcnt(0)" ::: "memory");                \
        }                                                                     \
        if (b == cc) {                                                        \
            h_all[(size_t)want * H + e0] = h0v;                               \
            if (v1) h_all[(size_t)want * H + e1] = h1v;                       \
        }                                                                     \
        xi = xi_nxt;                                                          \
    }

        for (int tb = 0; tb < TT; tb += PRING) {
            RSTEP(tb + 1, 1, old1)
            RSTEP(tb + 2, 2, old2)
            RSTEP(tb + 3, 3, old3)
            RSTEP(tb + 4, 0, old0)
        }
#undef RSTEP
    }
#undef FMA128

    if (b == cc && rl == 0)
        __hip_atomic_fetch_add(done, 1, __ATOMIC_RELAXED,
                               __HIP_MEMORY_SCOPE_AGENT);
}

// ---------------------------------------------------------------------------
// FALLBACK: proven R3 agent-scope path (15.2ms). Skipped iff the fast cohort
// fully completed (done == 8) and the fast path was attempted (fail == 0).
// ---------------------------------------------------------------------------
#define FB_RING 4
__global__ __launch_bounds__(64) void rnn_fb(
    const int*   __restrict__ x_idx,
    const float* __restrict__ W_xhT,
    const float* __restrict__ W_hh,
    const float* __restrict__ B_h,
    float*       __restrict__ h_all,
    u64*         __restrict__ pkt,     // FB_RING x 16 x 16 x SL
    const int*   __restrict__ fail,
    const int*   __restrict__ done)
{
    if (__hip_atomic_load(fail, __ATOMIC_RELAXED,
                          __HIP_MEMORY_SCOPE_AGENT) == 0 &&
        __hip_atomic_load(done, __ATOMIC_RELAXED,
                          __HIP_MEMORY_SCOPE_AGENT) == 8)
        return;                               // fast path delivered h_all

    const int rl  = threadIdx.x;
    const int b   = blockIdx.x >> 4;
    const int cc  = blockIdx.x & 15;
    const int row = b * SL + rl;
    const int r   = cc * SL + rl;
    const bool rowv = (row < H);
    const bool rv   = (r < H);

    float w[SL];
    const float* wrow = W_hh + (size_t)row * H;
    #pragma unroll
    for (int q = 0; q < SL / 4; ++q) {
        const int k = cc * SL + 4 * q;
        float4 v = make_float4(0.f, 0.f, 0.f, 0.f);
        if (rowv && (k + 3) < H) v = *(const float4*)(wrow + k);
        w[4*q+0] = v.x; w[4*q+1] = v.y; w[4*q+2] = v.z; w[4*q+3] = v.w;
    }
    const float bh = rv ? B_h[r] : 0.f;

    __shared__ float sh[SL];
    sh[rl] = rv ? h_all[r] : 0.f;
    asm volatile("s_waitcnt lgkmcnt(0)" ::: "memory");

    int xi = x_idx[0];
    for (int t = 0; t < TT; ++t) {
        const unsigned want = (unsigned)(t + 1);
        const int slot = (int)(want & (FB_RING - 1));
        int xi_nxt = xi;
        if (t + 1 < TT) xi_nxt = x_idx[t + 1];
        float xh = 0.f;
        if (rv) xh = W_xhT[(size_t)xi * H + r];

        float a0 = 0.f, a1 = 0.f, a2 = 0.f, a3 = 0.f;
        const float4* hb = (const float4*)sh;
        #pragma unroll
        for (int q = 0; q < SL / 4; ++q) {
            const float4 hv4 = hb[q];
            a0 += w[4*q+0] * hv4.x;
            a1 += w[4*q+1] * hv4.y;
            a2 += w[4*q+2] * hv4.z;
            a3 += w[4*q+3] * hv4.w;
        }
        const float a = (a0 + a1) + (a2 + a3);

        __hip_atomic_store(pkt + (((size_t)slot * 16 + b) * 16 + cc) * SL + rl,
                           ((u64)want << 32) | (u64)__float_as_uint(a),
                           __ATOMIC_RELAXED, __HIP_MEMORY_SCOPE_AGENT);

        const u64* base = pkt + ((size_t)slot * 16 + cc) * 16 * SL + rl;
        u64 p[16];
        for (;;) {
            #pragma unroll
            for (int j = 0; j < 16; ++j)
                p[j] = __hip_atomic_load(base + j * SL, __ATOMIC_RELAXED,
                                         __HIP_MEMORY_SCOPE_AGENT);
            bool ok = true;
            #pragma unroll
            for (int j = 0; j < 16; ++j)
                ok &= ((unsigned)(p[j] >> 32) == want);
            if (__all(ok)) break;
        }

        float s = xh + bh;
        #pragma unroll
        for (int j = 0; j < 16; ++j) s += __uint_as_float((unsigned)p[j]);
        const float hv = rv ? tanhf(s) : 0.f;
        if (b == cc && rv) h_all[(size_t)want * H + r] = hv;
        sh[rl] = hv;
        asm volatile("s_waitcnt lgkmcnt(0)" ::: "memory");
        xi = xi_nxt;
    }
}

// ---------------------------------------------------------------------------
__global__ __launch_bounds__(256) void transpose_wxh(
    const float* __restrict__ W_xh, float* __restrict__ W_xhT)
{
    const int idx = blockIdx.x * 256 + threadIdx.x;
    if (idx < NC * H) {
        const int c = idx / H, r = idx % H;
        W_xhT[idx] = W_xh[r * NC + c];
    }
}

__global__ __launch_bounds__(256) void transpose_why(
    const float* __restrict__ W_hy, float* __restrict__ WhyT)
{
    const int idx = blockIdx.x * 256 + threadIdx.x;
    if (idx < NC * H) {
        const int k = idx / NC, n = idx % NC;
        WhyT[idx] = W_hy[n * H + k];
    }
}

__global__ __launch_bounds__(256) void out_gemm(
    const float* __restrict__ h_all,
    const float* __restrict__ WhyT,   // padded by >=16 floats
    float*       __restrict__ out)
{
    __shared__ float hs[TM * H];      // 64000 B
    const int t0 = blockIdx.x * TM;
    const int nt = min(TM, (TT + 1) - t0);

    const float4* src = (const float4*)(h_all + (size_t)t0 * H);
    const int total4 = nt * H / 4;
    for (int i = threadIdx.x; i < total4; i += 256)
        ((float4*)hs)[i] = src[i];
    __syncthreads();

    const int tl = threadIdx.x >> 4;
    const int ng = threadIdx.x & 15;
    if (tl < nt) {
        float acc0 = 0.f, acc1 = 0.f, acc2 = 0.f, acc3 = 0.f, acc4 = 0.f;
        const float* hrow = hs + tl * H;
        #pragma unroll 4
        for (int k = 0; k < H; ++k) {
            const float hv = hrow[k];
            const float* wr = WhyT + k * NC + ng;
            acc0 += hv * wr[0];
            acc1 += hv * wr[16];
            acc2 += hv * wr[32];
            acc3 += hv * wr[48];
            acc4 += hv * wr[64];
        }
        float* orow = out + (size_t)(t0 + tl) * NC + ng;
        orow[0]  = acc0;
        orow[16] = acc1;
        orow[32] = acc2;
        orow[48] = acc3;
        if (ng < 4) orow[64] = acc4;
    }
}

// ---------------------------------------------------------------------------
extern "C" void kernel_launch(void* const* d_in, const int* in_sizes, int n_in,
                              void* d_out, int out_size, void* d_ws, size_t ws_size,
                              hipStream_t stream)
{
    const int*   x_idx = (const int*)  d_in[0];
    const float* h0    = (const float*)d_in[1];
    const float* W_xh  = (const float*)d_in[2];
    const float* W_hh  = (const float*)d_in[3];
    const float* W_hy  = (const float*)d_in[4];
    const float* B_h   = (const float*)d_in[5];
    float* out = (float*)d_out;

    char* ws = (char*)d_ws;
    size_t off = 0;
    auto take = [&](size_t bytes) {
        void* p = ws + off;
        off = (off + bytes + 255) & ~(size_t)255;
        return p;
    };
    float* h_all  = (float*)take((size_t)(TT + 1) * H * sizeof(float));
    float* WhyT   = (float*)take((size_t)(NC * H + 32) * sizeof(float));
    float* W_xhT  = (float*)take((size_t)(NC * H) * sizeof(float));
    const size_t fb_bytes = (size_t)FB_RING * 16 * 16 * SL * sizeof(u64);
    u64*   pkt_fb = (u64*)take(fb_bytes);
    int*   fail   = (int*)take(64);
    int*   done   = (int*)take(64);
    int*   ctrl   = (int*)take(256);       // own cache lines
    u64*   probe  = (u64*)take(256);       // own cache line (may go L2-dirty)
    const size_t at_bytes = (size_t)PRING * HP * sizeof(u64);        // 32 KB
    u64*   pkt_at = (u64*)take(at_bytes);
    const size_t st_bytes = (size_t)PRING * 16 * 8 * 64 * sizeof(u64); // 256 KB
    u64*   pkt_st = (u64*)take(st_bytes);
    const size_t need_fast = off;

    hipMemcpyAsync(h_all, h0, H * sizeof(float),
                   hipMemcpyDeviceToDevice, stream);
    transpose_wxh<<<(NC * H + 255) / 256, 256, 0, stream>>>(W_xh, W_xhT);
    transpose_why<<<(NC * H + 255) / 256, 256, 0, stream>>>(W_hy, WhyT);

    hipMemsetAsync(pkt_fb, 0, fb_bytes, stream);
    hipMemsetAsync(done, 0, 64, stream);
    if (ws_size >= need_fast) {
        hipMemsetAsync(pkt_at, 0, at_bytes, stream);
        hipMemsetAsync(ctrl, 0, 256, stream);
        hipMemsetAsync(probe, 0, 256, stream);
        hipMemsetAsync(fail, 0, 64, stream);
        rnn_fast<<<GRID_FAST, SL, 0, stream>>>(x_idx, W_xhT, W_hh, B_h,
                                               h_all, pkt_at, pkt_st,
                                               ctrl, probe, done);
    } else {
        hipMemsetAsync(fail, 1, 4, stream);    // force fallback
    }
    rnn_fb<<<256, SL, 0, stream>>>(x_idx, W_xhT, W_hh, B_h,
                                   h_all, pkt_fb, fail, done);
    out_gemm<<<(TT + 1 + TM - 1) / TM, 256, 0, stream>>>(h_all, WhyT, out);
}

// Round 7
// 18930.002 us; speedup vs baseline: 1.6895x; 1.5522x over previous
//
#include <hip/hip_runtime.h>
#include <hip/hip_bf16.h>

#define H      1000          // hidden dim
#define HP     1024          // padded hidden
#define TT     8192          // seq len
#define NC     68            // num chars
#define SL     64            // wave size
#define NWAVE  128           // 16 row slices x 8 col chunks
#define PRING  4             // packet ring slots
#define POLL_LIMIT 32768u    // sweeps before declaring the fast path dead
#define PF_LIMIT   8192u     // preflight inv+load probe sweeps
#define BAR_LIMIT  16384u    // barrier spin limit (agent loads)
#define TM     16            // t-tile for output gemm
#define GRID_FAST 2048       // oversubscribed launch; cohort self-assembles on XCD 0
#define PF_MAGIC 0x1DEADBEEFull

typedef unsigned long long u64;
typedef long long ll;

// ---------------------------------------------------------------------------
// FAST PATH v7: maximum round-3 fidelity + batched poll + mode telemetry.
//
// Evidence ledger:
//   r3 (ONLY proven L2-resident run: WRITE=32MB, FETCH=6.7MB, completed):
//       preflight = {rank0 plain store BEFORE bar; inv + PLAIN load poll};
//       main poll = buffer_inv sc0 + VOLATILE loads, which LLVM emits as
//       global_load_dwordx2 ... sc0 sc1 — each followed by its own
//       s_waitcnt vmcnt(0) (the 16x serialization = r3's only flaw).
//   r4/5/6 (WRITE=556MB, 30-60ms, mechanism UNRESOLVED): all changed BOTH
//       the preflight (added L1-prime, store after bar) and the load flavor
//       (sc0-only / plain). 556,308KB fits both "in-kernel MALL mode ran"
//       and "stores HBM-routed" within 0.2% -- indistinguishable.
//
// v7 therefore replicates r3 EXACTLY except batching the poll:
//   - preflight byte-for-byte r3 (store -> bar1 -> inv+plain-load poll ->
//     flag -> bar2 -> consensus)
//   - main poll: buffer_inv sc0 + 16x global_load_dwordx2 sc0 sc1 (the
//     volatile flavor) + ONE s_waitcnt vmcnt(0)  == r3's instruction
//     sequence with 1 round trip instead of 16.
//   - publish: plain coalesced store, wave-contiguous 512B (r3/r6 pattern).
//   - NO in-kernel MALL mode: preflight failure => immediate exit =>
//     rnn_fast duration + rnn_fb presence become mode telemetry.
//
// Layout pkt_st[slot][group=e>>6][producer cc'][r=e&63]:
//   producer (b,cc) lane rl stores ((want<<32)|f32bits(a)) at
//   slot*8192 + (b*8+cc)*64 + rl     (contiguous 512B per wave);
//   consumer of e0=cc*128+rl polls 8 tags at slot*8192 + (2cc*8+j)*64 + rl,
//   j-stride 512B (imm offsets 0..3584), e1 at group 2cc+1.
//
// Correctness: tags absolute; payload rides in the same 8B word; consumer
// breaks when all 16 tags == want; fixed j-order sum + base depending only
// on (cc,rl) => the 16 redundant finalizers (b=0..15) compute bit-identical
// h. Self-zero of pkt_st kills cross-run stale tags. Ring safety (PRING=4):
// a producer storing @want+4 completed its poll @want+3, which transitively
// spans ALL 16 slices at @want+2 => no poller of `want` sees a later
// generation.
//
// Liveness: all spins bounded; any overrun => wave returns; done stays < 8
// => proven fallback recomputes ALL of h_all. No hang possible.
// ---------------------------------------------------------------------------

__device__ __forceinline__ bool bar_wait(int* ctr, int rl)
{
    // drain own vm ops so everything published is complete before arrival
    asm volatile("s_waitcnt vmcnt(0)" ::: "memory");
    if (rl == 0)
        __hip_atomic_fetch_add(ctr, 1, __ATOMIC_RELAXED,
                               __HIP_MEMORY_SCOPE_AGENT);
    unsigned n = 0;
    while (__hip_atomic_load(ctr, __ATOMIC_RELAXED,
                             __HIP_MEMORY_SCOPE_AGENT) < NWAVE) {
        if (++n > BAR_LIMIT) return false;
    }
    return true;
}

__global__ __launch_bounds__(64, 1) void rnn_fast(
    const int*   __restrict__ x_idx,
    const float* __restrict__ W_xhT,   // NC x H
    const float* __restrict__ W_hh,
    const float* __restrict__ B_h,
    float*       __restrict__ h_all,   // (TT+1) x H
    u64*         __restrict__ pkt_st,  // [PRING][16][8][64]
    int*         __restrict__ ctrl,    // [0]=claim [1..3]=bars [4]=failINV
    u64*         __restrict__ probe,   // preflight line (own 256B region)
    int*         __restrict__ done)    // completion counter, pre-zeroed
{
    // --- cohort self-assembly on XCD 0 ---
    unsigned xcc;
    asm volatile("s_getreg_b32 %0, hwreg(HW_REG_XCC_ID)" : "=s"(xcc));
    if ((xcc & 7u) != 0u) return;

    const int rl = threadIdx.x;
    int rank = 0;
    if (rl == 0)
        rank = __hip_atomic_fetch_add(&ctrl[0], 1, __ATOMIC_RELAXED,
                                      __HIP_MEMORY_SCOPE_AGENT);
    rank = __builtin_amdgcn_readfirstlane(rank);
    if (rank >= NWAVE) return;

    // --- preflight: EXACT r3 sequence ---
    if (rank == 0 && rl == 0)
        *probe = PF_MAGIC;               // plain store; bar1's vmcnt drains it

    if (!bar_wait(&ctrl[1], rl)) return;

    bool okI = false;
    {
        u64 pv = 0;
        for (unsigned n = 0; n < PF_LIMIT; ++n) {
            asm volatile(
                "buffer_inv sc0\n\t"
                "global_load_dwordx2 %0, %1, off\n\t"
                "s_waitcnt vmcnt(0)"
                : "=&v"(pv) : "v"(probe) : "memory");
            if (pv == (u64)PF_MAGIC) { okI = true; break; }
        }
    }
    if (!okI && rl == 0)
        __hip_atomic_fetch_add(&ctrl[4], 1, __ATOMIC_RELAXED,
                               __HIP_MEMORY_SCOPE_AGENT);
    if (!bar_wait(&ctrl[2], rl)) return;
    const bool modeINV =
        (__hip_atomic_load(&ctrl[4], __ATOMIC_RELAXED,
                           __HIP_MEMORY_SCOPE_AGENT) == 0);
    if (!modeINV) return;   // TELEMETRY: fast exit => rnn_fb runs (15 ms)

    // --- setup ---
    const int b  = rank >> 3;                 // row slice 0..15
    const int cc = rank & 7;                  // col chunk 0..7
    const int row = b * SL + rl;              // producer row (<= 1023)
    const int e0  = cc * 128 + rl;            // consumer elements (e0 <= 959)
    const int e1  = e0 + 64;                  // (e1 <= 1023)
    const bool rowv = (row < H);
    const bool v1   = (e1 < H);

    float w[128];
    const float* wrow = W_hh + (size_t)row * H;
    #pragma unroll
    for (int q = 0; q < 32; ++q) {
        const int k = cc * 128 + 4 * q;
        float4 v = make_float4(0.f, 0.f, 0.f, 0.f);
        if (rowv && (k + 3) < H) v = *(const float4*)(wrow + k);
        w[4*q+0] = v.x; w[4*q+1] = v.y; w[4*q+2] = v.z; w[4*q+3] = v.w;
    }
    const float bi0 = B_h[e0];
    const float bi1 = v1 ? B_h[e1] : 0.f;

    __shared__ float sh[128];                 // my h-chunk
    sh[rl]      = h_all[e0];
    sh[64 + rl] = v1 ? h_all[e1] : 0.f;
    asm volatile("s_waitcnt lgkmcnt(0)" ::: "memory");

    int xi = x_idx[0];

    // ---- self-zero pkt_st (kills cross-run stale tags) ----
    const int gid = rank * SL + rl;               // 0..8191
    #pragma unroll
    for (int z = 0; z < 4; ++z)
        pkt_st[(size_t)z * 8192 + gid] = 0;       // 4*8192 = 32768 u64
    if (!bar_wait(&ctrl[3], rl)) return;

    const size_t slot_stride = 16 * 8 * 64;       // u64 per ring slot

    // ---- main loop ----
    for (int t = 1; t <= TT; ++t) {
        const int want = t;
        int xi_nxt = xi;
        if (want < TT) xi_nxt = x_idx[want];
        const float xh0 = W_xhT[(size_t)xi * H + e0];
        const float xh1 = v1 ? W_xhT[(size_t)xi * H + e1] : 0.f;

        float a;
        {
            float a0 = 0.f, a1 = 0.f, a2 = 0.f, a3 = 0.f;
            const float4* hb = (const float4*)sh;
            #pragma unroll
            for (int q = 0; q < 32; ++q) {
                const float4 hv4 = hb[q];
                a0 += w[4*q+0] * hv4.x;
                a1 += w[4*q+1] * hv4.y;
                a2 += w[4*q+2] * hv4.z;
                a3 += w[4*q+3] * hv4.w;
            }
            a = (a0 + a1) + (a2 + a3);
        }

        const int slot = want & (PRING - 1);
        // publish: wave-contiguous 512B plain store (r3/r6-proven pattern)
        pkt_st[slot * slot_stride + (((size_t)b * 8 + cc) * 64) + rl] =
            ((u64)(unsigned)want << 32) | (u64)__float_as_uint(a);
        asm volatile("" ::: "memory");

        // poll: inv + 16x dwordx2 sc0 sc1 (r3's volatile flavor), ONE waitcnt
        const u64* base0 = pkt_st + slot * slot_stride
                         + ((size_t)(2 * cc)     * 8) * 64 + rl;
        const u64* base1 = pkt_st + slot * slot_stride
                         + ((size_t)(2 * cc + 1) * 8) * 64 + rl;
        u64 p00, p01, p02, p03, p04, p05, p06, p07;
        u64 p10, p11, p12, p13, p14, p15, p16, p17;
        const unsigned wtag = (unsigned)want;
        unsigned sweeps = 0;
        for (;;) {
            asm volatile(
                "buffer_inv sc0\n\t"
                "global_load_dwordx2 %0, %16, off sc0 sc1\n\t"
                "global_load_dwordx2 %1, %16, off offset:512 sc0 sc1\n\t"
                "global_load_dwordx2 %2, %16, off offset:1024 sc0 sc1\n\t"
                "global_load_dwordx2 %3, %16, off offset:1536 sc0 sc1\n\t"
                "global_load_dwordx2 %4, %16, off offset:2048 sc0 sc1\n\t"
                "global_load_dwordx2 %5, %16, off offset:2560 sc0 sc1\n\t"
                "global_load_dwordx2 %6, %16, off offset:3072 sc0 sc1\n\t"
                "global_load_dwordx2 %7, %16, off offset:3584 sc0 sc1\n\t"
                "global_load_dwordx2 %8, %17, off sc0 sc1\n\t"
                "global_load_dwordx2 %9, %17, off offset:512 sc0 sc1\n\t"
                "global_load_dwordx2 %10, %17, off offset:1024 sc0 sc1\n\t"
                "global_load_dwordx2 %11, %17, off offset:1536 sc0 sc1\n\t"
                "global_load_dwordx2 %12, %17, off offset:2048 sc0 sc1\n\t"
                "global_load_dwordx2 %13, %17, off offset:2560 sc0 sc1\n\t"
                "global_load_dwordx2 %14, %17, off offset:3072 sc0 sc1\n\t"
                "global_load_dwordx2 %15, %17, off offset:3584 sc0 sc1\n\t"
                "s_waitcnt vmcnt(0)"
                : "=&v"(p00), "=&v"(p01), "=&v"(p02), "=&v"(p03),
                  "=&v"(p04), "=&v"(p05), "=&v"(p06), "=&v"(p07),
                  "=&v"(p10), "=&v"(p11), "=&v"(p12), "=&v"(p13),
                  "=&v"(p14), "=&v"(p15), "=&v"(p16), "=&v"(p17)
                : "v"(base0), "v"(base1)
                : "memory");
            bool ok = ((unsigned)(p00 >> 32) == wtag) &
                      ((unsigned)(p01 >> 32) == wtag) &
                      ((unsigned)(p02 >> 32) == wtag) &
                      ((unsigned)(p03 >> 32) == wtag) &
                      ((unsigned)(p04 >> 32) == wtag) &
                      ((unsigned)(p05 >> 32) == wtag) &
                      ((unsigned)(p06 >> 32) == wtag) &
                      ((unsigned)(p07 >> 32) == wtag) &
                      ((unsigned)(p10 >> 32) == wtag) &
                      ((unsigned)(p11 >> 32) == wtag) &
                      ((unsigned)(p12 >> 32) == wtag) &
                      ((unsigned)(p13 >> 32) == wtag) &
                      ((unsigned)(p14 >> 32) == wtag) &
                      ((unsigned)(p15 >> 32) == wtag) &
                      ((unsigned)(p16 >> 32) == wtag) &
                      ((unsigned)(p17 >> 32) == wtag);
            if (__all(ok)) break;
            if (++sweeps > POLL_LIMIT) return;   // cohort dead: bail
        }

        // fixed j-order sum => bit-identical across redundant finalizers
        float s0 = xh0 + bi0, s1 = xh1 + bi1;
        s0 += __uint_as_float((unsigned)p00);
        s0 += __uint_as_float((unsigned)p01);
        s0 += __uint_as_float((unsigned)p02);
        s0 += __uint_as_float((unsigned)p03);
        s0 += __uint_as_float((unsigned)p04);
        s0 += __uint_as_float((unsigned)p05);
        s0 += __uint_as_float((unsigned)p06);
        s0 += __uint_as_float((unsigned)p07);
        s1 += __uint_as_float((unsigned)p10);
        s1 += __uint_as_float((unsigned)p11);
        s1 += __uint_as_float((unsigned)p12);
        s1 += __uint_as_float((unsigned)p13);
        s1 += __uint_as_float((unsigned)p14);
        s1 += __uint_as_float((unsigned)p15);
        s1 += __uint_as_float((unsigned)p16);
        s1 += __uint_as_float((unsigned)p17);
        const float h0v = tanhf(s0);
        const float h1v = v1 ? tanhf(s1) : 0.f;
        if (want < TT) {
            sh[rl]      = h0v;
            sh[64 + rl] = h1v;
            asm volatile("s_waitcnt lgkmcnt(0)" ::: "memory");
        }
        if (b == cc) {                   // 8 designated writer waves
            h_all[(size_t)want * H + e0] = h0v;
            if (v1) h_all[(size_t)want * H + e1] = h1v;
        }
        xi = xi_nxt;
    }

    if (b == cc && rl == 0)
        __hip_atomic_fetch_add(done, 1, __ATOMIC_RELAXED,
                               __HIP_MEMORY_SCOPE_AGENT);
}

// ---------------------------------------------------------------------------
// FALLBACK: proven R3 agent-scope path (15.2ms). Skipped iff the fast cohort
// fully completed (done == 8) and the fast path was attempted (fail == 0).
// ---------------------------------------------------------------------------
#define FB_RING 4
__global__ __launch_bounds__(64) void rnn_fb(
    const int*   __restrict__ x_idx,
    const float* __restrict__ W_xhT,
    const float* __restrict__ W_hh,
    const float* __restrict__ B_h,
    float*       __restrict__ h_all,
    u64*         __restrict__ pkt,     // FB_RING x 16 x 16 x SL
    const int*   __restrict__ fail,
    const int*   __restrict__ done)
{
    if (__hip_atomic_load(fail, __ATOMIC_RELAXED,
                          __HIP_MEMORY_SCOPE_AGENT) == 0 &&
        __hip_atomic_load(done, __ATOMIC_RELAXED,
                          __HIP_MEMORY_SCOPE_AGENT) == 8)
        return;                               // fast path delivered h_all

    const int rl  = threadIdx.x;
    const int b   = blockIdx.x >> 4;
    const int cc  = blockIdx.x & 15;
    const int row = b * SL + rl;
    const int r   = cc * SL + rl;
    const bool rowv = (row < H);
    const bool rv   = (r < H);

    float w[SL];
    const float* wrow = W_hh + (size_t)row * H;
    #pragma unroll
    for (int q = 0; q < SL / 4; ++q) {
        const int k = cc * SL + 4 * q;
        float4 v = make_float4(0.f, 0.f, 0.f, 0.f);
        if (rowv && (k + 3) < H) v = *(const float4*)(wrow + k);
        w[4*q+0] = v.x; w[4*q+1] = v.y; w[4*q+2] = v.z; w[4*q+3] = v.w;
    }
    const float bh = rv ? B_h[r] : 0.f;

    __shared__ float sh[SL];
    sh[rl] = rv ? h_all[r] : 0.f;
    asm volatile("s_waitcnt lgkmcnt(0)" ::: "memory");

    int xi = x_idx[0];
    for (int t = 0; t < TT; ++t) {
        const unsigned want = (unsigned)(t + 1);
        const int slot = (int)(want & (FB_RING - 1));
        int xi_nxt = xi;
        if (t + 1 < TT) xi_nxt = x_idx[t + 1];
        float xh = 0.f;
        if (rv) xh = W_xhT[(size_t)xi * H + r];

        float a0 = 0.f, a1 = 0.f, a2 = 0.f, a3 = 0.f;
        const float4* hb = (const float4*)sh;
        #pragma unroll
        for (int q = 0; q < SL / 4; ++q) {
            const float4 hv4 = hb[q];
            a0 += w[4*q+0] * hv4.x;
            a1 += w[4*q+1] * hv4.y;
            a2 += w[4*q+2] * hv4.z;
            a3 += w[4*q+3] * hv4.w;
        }
        const float a = (a0 + a1) + (a2 + a3);

        __hip_atomic_store(pkt + (((size_t)slot * 16 + b) * 16 + cc) * SL + rl,
                           ((u64)want << 32) | (u64)__float_as_uint(a),
                           __ATOMIC_RELAXED, __HIP_MEMORY_SCOPE_AGENT);

        const u64* base = pkt + ((size_t)slot * 16 + cc) * 16 * SL + rl;
        u64 p[16];
        for (;;) {
            #pragma unroll
            for (int j = 0; j < 16; ++j)
                p[j] = __hip_atomic_load(base + j * SL, __ATOMIC_RELAXED,
                                         __HIP_MEMORY_SCOPE_AGENT);
            bool ok = true;
            #pragma unroll
            for (int j = 0; j < 16; ++j)
                ok &= ((unsigned)(p[j] >> 32) == want);
            if (__all(ok)) break;
        }

        float s = xh + bh;
        #pragma unroll
        for (int j = 0; j < 16; ++j) s += __uint_as_float((unsigned)p[j]);
        const float hv = rv ? tanhf(s) : 0.f;
        if (b == cc && rv) h_all[(size_t)want * H + r] = hv;
        sh[rl] = hv;
        asm volatile("s_waitcnt lgkmcnt(0)" ::: "memory");
        xi = xi_nxt;
    }
}

// ---------------------------------------------------------------------------
__global__ __launch_bounds__(256) void transpose_wxh(
    const float* __restrict__ W_xh, float* __restrict__ W_xhT)
{
    const int idx = blockIdx.x * 256 + threadIdx.x;
    if (idx < NC * H) {
        const int c = idx / H, r = idx % H;
        W_xhT[idx] = W_xh[r * NC + c];
    }
}

__global__ __launch_bounds__(256) void transpose_why(
    const float* __restrict__ W_hy, float* __restrict__ WhyT)
{
    const int idx = blockIdx.x * 256 + threadIdx.x;
    if (idx < NC * H) {
        const int k = idx / NC, n = idx % NC;
        WhyT[idx] = W_hy[n * H + k];
    }
}

__global__ __launch_bounds__(256) void out_gemm(
    const float* __restrict__ h_all,
    const float* __restrict__ WhyT,   // padded by >=16 floats
    float*       __restrict__ out)
{
    __shared__ float hs[TM * H];      // 64000 B
    const int t0 = blockIdx.x * TM;
    const int nt = min(TM, (TT + 1) - t0);

    const float4* src = (const float4*)(h_all + (size_t)t0 * H);
    const int total4 = nt * H / 4;
    for (int i = threadIdx.x; i < total4; i += 256)
        ((float4*)hs)[i] = src[i];
    __syncthreads();

    const int tl = threadIdx.x >> 4;
    const int ng = threadIdx.x & 15;
    if (tl < nt) {
        float acc0 = 0.f, acc1 = 0.f, acc2 = 0.f, acc3 = 0.f, acc4 = 0.f;
        const float* hrow = hs + tl * H;
        #pragma unroll 4
        for (int k = 0; k < H; ++k) {
            const float hv = hrow[k];
            const float* wr = WhyT + k * NC + ng;
            acc0 += hv * wr[0];
            acc1 += hv * wr[16];
            acc2 += hv * wr[32];
            acc3 += hv * wr[48];
            acc4 += hv * wr[64];
        }
        float* orow = out + (size_t)(t0 + tl) * NC + ng;
        orow[0]  = acc0;
        orow[16] = acc1;
        orow[32] = acc2;
        orow[48] = acc3;
        if (ng < 4) orow[64] = acc4;
    }
}

// ---------------------------------------------------------------------------
extern "C" void kernel_launch(void* const* d_in, const int* in_sizes, int n_in,
                              void* d_out, int out_size, void* d_ws, size_t ws_size,
                              hipStream_t stream)
{
    const int*   x_idx = (const int*)  d_in[0];
    const float* h0    = (const float*)d_in[1];
    const float* W_xh  = (const float*)d_in[2];
    const float* W_hh  = (const float*)d_in[3];
    const float* W_hy  = (const float*)d_in[4];
    const float* B_h   = (const float*)d_in[5];
    float* out = (float*)d_out;

    char* ws = (char*)d_ws;
    size_t off = 0;
    auto take = [&](size_t bytes) {
        void* p = ws + off;
        off = (off + bytes + 255) & ~(size_t)255;
        return p;
    };
    float* h_all  = (float*)take((size_t)(TT + 1) * H * sizeof(float));
    float* WhyT   = (float*)take((size_t)(NC * H + 32) * sizeof(float));
    float* W_xhT  = (float*)take((size_t)(NC * H) * sizeof(float));
    const size_t fb_bytes = (size_t)FB_RING * 16 * 16 * SL * sizeof(u64);
    u64*   pkt_fb = (u64*)take(fb_bytes);
    int*   fail   = (int*)take(64);
    int*   done   = (int*)take(64);
    int*   ctrl   = (int*)take(256);       // own cache lines
    u64*   probe  = (u64*)take(256);       // own cache line (may go L2-dirty)
    const size_t st_bytes = (size_t)PRING * 16 * 8 * 64 * sizeof(u64); // 256 KB
    u64*   pkt_st = (u64*)take(st_bytes);
    const size_t need_fast = off;

    hipMemcpyAsync(h_all, h0, H * sizeof(float),
                   hipMemcpyDeviceToDevice, stream);
    transpose_wxh<<<(NC * H + 255) / 256, 256, 0, stream>>>(W_xh, W_xhT);
    transpose_why<<<(NC * H + 255) / 256, 256, 0, stream>>>(W_hy, WhyT);

    hipMemsetAsync(pkt_fb, 0, fb_bytes, stream);
    hipMemsetAsync(done, 0, 64, stream);
    if (ws_size >= need_fast) {
        hipMemsetAsync(ctrl, 0, 256, stream);
        hipMemsetAsync(probe, 0, 256, stream);
        hipMemsetAsync(fail, 0, 64, stream);
        rnn_fast<<<GRID_FAST, SL, 0, stream>>>(x_idx, W_xhT, W_hh, B_h,
                                               h_all, pkt_st,
                                               ctrl, probe, done);
    } else {
        hipMemsetAsync(fail, 1, 4, stream);    // force fallback
    }
    rnn_fb<<<256, SL, 0, stream>>>(x_idx, W_xhT, W_hh, B_h,
                                   h_all, pkt_fb, fail, done);
    out_gemm<<<(TT + 1 + TM - 1) / TM, 256, 0, stream>>>(h_all, WhyT, out);
}